// Round 1
// baseline (8659.819 us; speedup 1.0000x reference)
//
#include <hip/hip_runtime.h>
#include <cstdint>
#include <cstddef>

// ---------------- problem constants (fixed by reference) ----------------
#define D_N     1024            // neighbors
#define K_S     128             // seq len per neighbor
#define EDIM    384
#define HID     128
#define NHEAD   4
#define HDIM    32
#define FFD     128
#define NLAYER  2
#define ETOT    (D_N * K_S)     // 131072 edges
#define NNODES  200000
#define NBINS   (2 * D_N + 2)   // sort keys 0..2049
#define NCH     512             // chunks for stable counting sort
#define CHL     (ETOT / NCH)    // 256 edges per chunk

// LDS col offsets inside o_s during attention (16B-aligned)
#define KOFF 0
#define VOFF 36

// ---------------- workspace layout (bytes) ----------------
#define OFF_ORDER 0u            // int[131072]
#define OFF_KEY   (1u << 19)    // int[131072]
#define OFF_SLOT  (1u << 20)    // int[200000]
#define OFF_HIST  (1u << 21)    // int[NBINS*NCH] = 1,049,600
#define OFF_POOL  (7u << 20)    // float[1024*128]

// ============================================================
// P0: init slot[] = D and zero hist[]
// ============================================================
__global__ void init_ws(int* __restrict__ slot, int* __restrict__ hist)
{
    int idx = blockIdx.x * blockDim.x + threadIdx.x;
    int stride = gridDim.x * blockDim.x;
    for (int i = idx; i < NBINS * NCH; i += stride) hist[i] = 0;
    for (int i = idx; i < NNODES; i += stride) slot[i] = D_N;
}

// ============================================================
// P1: find first D tgt-edges (stable), set slot[neigh_node] = rank
// ============================================================
__global__ void find_neigh(const int* __restrict__ eidx,
                           const int* __restrict__ tgt_idx,
                           int* __restrict__ slot)
{
    __shared__ int cnt[1024];
    __shared__ int neigh[D_N];
    const int tid = threadIdx.x;
    const int tgt = tgt_idx[0];
    const int* src = eidx;
    const int* dst = eidx + ETOT;
    const int epc = ETOT / 1024;           // 128
    const int e0 = tid * epc;

    int c = 0;
    for (int e = e0; e < e0 + epc; ++e) c += (src[e] == tgt) ? 1 : 0;
    cnt[tid] = c;
    __syncthreads();
    // inclusive scan (Hillis-Steele)
    for (int s = 1; s < 1024; s <<= 1) {
        int add = (tid >= s) ? cnt[tid - s] : 0;
        __syncthreads();
        cnt[tid] += add;
        __syncthreads();
    }
    int base = cnt[tid] - c;               // exclusive
    int r = base;
    for (int e = e0; e < e0 + epc; ++e) {
        if (src[e] == tgt) { if (r < D_N) neigh[r] = dst[e]; ++r; }
    }
    __syncthreads();
    int total = cnt[1023];
    if (tid < total && tid < D_N) slot[neigh[tid]] = tid;
}

// ============================================================
// P2: per-chunk histogram of sort keys (run-length to avoid RMW chains)
// ============================================================
__global__ void hist_build(const int* __restrict__ eidx,
                           const int* __restrict__ tgt_idx,
                           const int* __restrict__ slot,
                           int* __restrict__ key,
                           int* __restrict__ hist)
{
    const int c = blockIdx.x * blockDim.x + threadIdx.x;
    if (c >= NCH) return;
    const int tgt = tgt_idx[0];
    const int* src = eidx;
    const int* dst = eidx + ETOT;
    const int e0 = c * CHL;
    int cur = -1, run = 0;
    for (int e = e0; e < e0 + CHL; ++e) {
        int k = slot[dst[e]] * 2 + ((src[e] != tgt) ? 1 : 0);
        key[e] = k;
        if (k == cur) { ++run; }
        else {
            if (run) hist[cur * NCH + c] += run;
            cur = k; run = 1;
        }
    }
    if (run) hist[cur * NCH + c] += run;
}

// ============================================================
// P3: scan — bin totals, exclusive bin bases, per-(bin,chunk) offsets
// ============================================================
__global__ void scan_hist(int* __restrict__ hist)
{
    __shared__ int tot[NBINS];
    __shared__ int bA[NBINS];
    __shared__ int bB[NBINS];
    const int tid = threadIdx.x;   // 1024

    for (int b = tid; b < NBINS; b += 1024) {
        int s = 0;
        for (int c = 0; c < NCH; ++c) s += hist[b * NCH + c];
        tot[b] = s; bA[b] = s;
    }
    __syncthreads();
    int* cur = bA; int* nxt = bB;
    for (int s = 1; s < NBINS; s <<= 1) {
        for (int idx = tid; idx < NBINS; idx += 1024) {
            int v = cur[idx];
            if (idx >= s) v += cur[idx - s];
            nxt[idx] = v;
        }
        __syncthreads();
        int* t = cur; cur = nxt; nxt = t;
    }
    // cur = inclusive scan; exclusive base = incl - tot
    for (int b = tid; b < NBINS; b += 1024) {
        int running = cur[b] - tot[b];
        for (int c = 0; c < NCH; ++c) {
            int tmp = hist[b * NCH + c];
            hist[b * NCH + c] = running;
            running += tmp;
        }
    }
}

// ============================================================
// P4: stable scatter -> order[]
// ============================================================
__global__ void scatter_order(const int* __restrict__ key,
                              int* __restrict__ hist,
                              int* __restrict__ order)
{
    const int c = blockIdx.x * blockDim.x + threadIdx.x;
    if (c >= NCH) return;
    const int e0 = c * CHL;
    int cur = -1, pos = 0;
    for (int e = e0; e < e0 + CHL; ++e) {
        int k = key[e];
        if (k != cur) {
            if (cur >= 0) hist[cur * NCH + c] = pos;
            cur = k;
            pos = hist[k * NCH + c];
        }
        if (pos >= 0 && pos < ETOT) order[pos] = e;
        ++pos;
    }
    if (cur >= 0) hist[cur * NCH + c] = pos;
}

// ============================================================
// GEMM helper: acc[o] += sum_e lrow[e] * W[(o)*wstride + e], e in [0,klen)
// lrow in LDS, W in global. Fully unrolled over outputs (static acc idx).
// ============================================================
template<int NOUT>
__device__ __forceinline__ void gemm_acc(float* acc, const float* lrow, int klen,
                                         const float* __restrict__ wbase, int wstride)
{
    for (int eb = 0; eb < klen; eb += 16) {
        float hr[16];
        #pragma unroll
        for (int t = 0; t < 16; t += 4) {
            float4 v = *(const float4*)&lrow[eb + t];
            hr[t] = v.x; hr[t+1] = v.y; hr[t+2] = v.z; hr[t+3] = v.w;
        }
        #pragma unroll
        for (int o = 0; o < NOUT; ++o) {
            const float* w = wbase + (size_t)o * wstride + eb;
            float4 w0 = *(const float4*)(w);
            float4 w1 = *(const float4*)(w + 4);
            float4 w2 = *(const float4*)(w + 8);
            float4 w3 = *(const float4*)(w + 12);
            acc[o] += hr[0]*w0.x + hr[1]*w0.y + hr[2]*w0.z + hr[3]*w0.w
                    + hr[4]*w1.x + hr[5]*w1.y + hr[6]*w1.z + hr[7]*w1.w
                    + hr[8]*w2.x + hr[9]*w2.y + hr[10]*w2.z + hr[11]*w2.w
                    + hr[12]*w3.x + hr[13]*w3.y + hr[14]*w3.z + hr[15]*w3.w;
        }
    }
}

// ============================================================
// P5: fused per-neighbor transformer. 1024 WGs x 256 threads.
// thread (i = tid>>1, half = tid&1) owns token row i, feature half fb=half*64.
// ============================================================
__global__ __launch_bounds__(256, 1) void fused_transformer(
    const float* __restrict__ edge_attrs,
    const float* __restrict__ ftm,
    const float* __restrict__ proj_w,    const float* __restrict__ proj_b,
    const float* __restrict__ attn_in_w, const float* __restrict__ attn_in_b,
    const float* __restrict__ attn_out_w,const float* __restrict__ attn_out_b,
    const float* __restrict__ ln1_g,     const float* __restrict__ ln1_b,
    const float* __restrict__ ff1_w,     const float* __restrict__ ff1_b,
    const float* __restrict__ ff2_w,     const float* __restrict__ ff2_b,
    const float* __restrict__ ln2_g,     const float* __restrict__ ln2_b,
    const int*   __restrict__ order,
    float*       __restrict__ pooled)
{
    __shared__ float h_s[128][132];   // residual stream (f32)
    __shared__ float o_s[128][132];   // staging: edge rows / k,v / o / ff1

    const int b    = blockIdx.x;
    const int tid  = threadIdx.x;
    const int i    = tid >> 1;
    const int half = tid & 1;
    const int fb   = half * 64;

    // ---------------- proj: h = rows @ proj_w^T + proj_b (+ marker) --------
    float acc[64];
    #pragma unroll
    for (int f = 0; f < 64; ++f) acc[f] = proj_b[fb + f];

    const int row = order[b * K_S + i];
    const float* arow = edge_attrs + (size_t)row * EDIM;

    for (int ch = 0; ch < 3; ++ch) {
        #pragma unroll
        for (int c = 0; c < 64; c += 4)
            *(float4*)&o_s[i][fb + c] = *(const float4*)&arow[ch * 128 + fb + c];
        __syncthreads();
        gemm_acc<64>(acc, &o_s[i][0], 128, proj_w + (size_t)fb * EDIM + ch * 128, EDIM);
        __syncthreads();
    }
    if (i == 0) {
        #pragma unroll
        for (int f = 0; f < 64; ++f) acc[f] += ftm[fb + f];
    }
    #pragma unroll
    for (int f = 0; f < 64; ++f) h_s[i][fb + f] = acc[f];
    __syncthreads();

    // ---------------- transformer layers ----------------------------------
    for (int l = 0; l < NLAYER; ++l) {
        const float* Win  = attn_in_w  + (size_t)l * 3 * HID * HID;
        const float* binb = attn_in_b  + l * 3 * HID;
        const float* Wout = attn_out_w + (size_t)l * HID * HID;
        const float* bout = attn_out_b + l * HID;

        float o_lo[32], o_hi[32];
        #pragma unroll
        for (int d = 0; d < 32; ++d) { o_lo[d] = 0.f; o_hi[d] = 0.f; }

        for (int head = 0; head < NHEAD; ++head) {
            // ---- q,k,v for this head (each thread: 16 of the 32 dims) ----
            const int d0 = half * 16;
            float qa[16], ka[16], va[16];
            #pragma unroll
            for (int dd = 0; dd < 16; ++dd) {
                qa[dd] = binb[            head * HDIM + d0 + dd];
                ka[dd] = binb[    HID  +  head * HDIM + d0 + dd];
                va[dd] = binb[2 * HID  +  head * HDIM + d0 + dd];
            }
            gemm_acc<16>(qa, &h_s[i][0], HID, Win + (size_t)(            head * HDIM + d0) * HID, HID);
            gemm_acc<16>(ka, &h_s[i][0], HID, Win + (size_t)(    HID  +  head * HDIM + d0) * HID, HID);
            gemm_acc<16>(va, &h_s[i][0], HID, Win + (size_t)(2 * HID  +  head * HDIM + d0) * HID, HID);
            #pragma unroll
            for (int dd = 0; dd < 16; ++dd) {
                o_s[i][KOFF + d0 + dd] = ka[dd];
                o_s[i][VOFF + d0 + dd] = va[dd];
            }
            // gather full q row into registers (uniform shfl, static select)
            float qo[16];
            #pragma unroll
            for (int dd = 0; dd < 16; ++dd) qo[dd] = __shfl_xor(qa[dd], 1);
            float qreg[32];
            #pragma unroll
            for (int dd = 0; dd < 16; ++dd) {
                qreg[dd]      = (half == 0) ? qa[dd] : qo[dd];
                qreg[16 + dd] = (half == 0) ? qo[dd] : qa[dd];
            }
            __syncthreads();

            // ---- scores: this thread handles j = fb..fb+63 ----
            float p[64];
            #pragma unroll
            for (int jj = 0; jj < 64; ++jj) {
                const float* kr = &o_s[fb + jj][KOFF];
                float s = 0.f;
                #pragma unroll
                for (int d = 0; d < 32; d += 4) {
                    float4 kv = *(const float4*)&kr[d];
                    s += qreg[d]*kv.x + qreg[d+1]*kv.y + qreg[d+2]*kv.z + qreg[d+3]*kv.w;
                }
                p[jj] = s * 0.17677669529663687f;   // 1/sqrt(32)
            }
            // ---- softmax across the 2-lane pair ----
            float m = -1e30f;
            #pragma unroll
            for (int jj = 0; jj < 64; ++jj) m = fmaxf(m, p[jj]);
            m = fmaxf(m, __shfl_xor(m, 1));
            float ssum = 0.f;
            #pragma unroll
            for (int jj = 0; jj < 64; ++jj) { float e = __expf(p[jj] - m); p[jj] = e; ssum += e; }
            ssum += __shfl_xor(ssum, 1);
            const float inv = 1.f / ssum;
            // ---- PV ----
            float oh[32];
            #pragma unroll
            for (int d = 0; d < 32; ++d) oh[d] = 0.f;
            #pragma unroll
            for (int jj = 0; jj < 64; ++jj) {
                const float* vr = &o_s[fb + jj][VOFF];
                const float pj = p[jj];
                #pragma unroll
                for (int d = 0; d < 32; d += 4) {
                    float4 vv = *(const float4*)&vr[d];
                    oh[d]   += pj * vv.x; oh[d+1] += pj * vv.y;
                    oh[d+2] += pj * vv.z; oh[d+3] += pj * vv.w;
                }
            }
            #pragma unroll
            for (int d = 0; d < 32; ++d) {
                float t = oh[d] + __shfl_xor(oh[d], 1);
                oh[d] = t * inv;
            }
            if ((head >> 1) == half) {
                if (head & 1) {
                    #pragma unroll
                    for (int d = 0; d < 32; ++d) o_hi[d] += oh[d];
                } else {
                    #pragma unroll
                    for (int d = 0; d < 32; ++d) o_lo[d] += oh[d];
                }
            }
            __syncthreads();   // before next head overwrites k/v staging
        }

        // ---- stage o, out-proj, residual, LN1 ----
        #pragma unroll
        for (int t = 0; t < 32; ++t) { o_s[i][fb + t] = o_lo[t]; o_s[i][fb + 32 + t] = o_hi[t]; }
        __syncthreads();

        float res[64];
        #pragma unroll
        for (int f = 0; f < 64; ++f) res[f] = bout[fb + f];
        gemm_acc<64>(res, &o_s[i][0], HID, Wout + (size_t)fb * HID, HID);

        float x[64];
        #pragma unroll
        for (int f = 0; f < 64; ++f) x[f] = h_s[i][fb + f] + res[f];

        float s1 = 0.f;
        #pragma unroll
        for (int f = 0; f < 64; ++f) s1 += x[f];
        s1 += __shfl_xor(s1, 1);
        const float mean = s1 * (1.f / 128.f);
        float s2 = 0.f;
        #pragma unroll
        for (int f = 0; f < 64; ++f) { float d = x[f] - mean; s2 += d * d; }
        s2 += __shfl_xor(s2, 1);
        const float rstd = rsqrtf(s2 * (1.f / 128.f) + 1e-5f);
        const float* g1  = ln1_g + l * HID;
        const float* bb1 = ln1_b + l * HID;
        #pragma unroll
        for (int f = 0; f < 64; ++f) {
            float v = (x[f] - mean) * rstd * g1[fb + f] + bb1[fb + f];
            x[f] = v;
            h_s[i][fb + f] = v;
        }
        __syncthreads();

        // ---- FF ----
        const float* W1  = ff1_w + (size_t)l * FFD * HID;
        const float* bf1 = ff1_b + l * FFD;
        const float* W2  = ff2_w + (size_t)l * HID * FFD;
        const float* bf2 = ff2_b + l * HID;

        float f1[64];
        #pragma unroll
        for (int j = 0; j < 64; ++j) f1[j] = bf1[fb + j];
        gemm_acc<64>(f1, &h_s[i][0], HID, W1 + (size_t)fb * HID, HID);
        #pragma unroll
        for (int j = 0; j < 64; ++j) o_s[i][fb + j] = fmaxf(f1[j], 0.f);
        __syncthreads();

        float r2[64];
        #pragma unroll
        for (int f = 0; f < 64; ++f) r2[f] = bf2[fb + f];
        gemm_acc<64>(r2, &o_s[i][0], FFD, W2 + (size_t)fb * FFD, FFD);
        #pragma unroll
        for (int f = 0; f < 64; ++f) x[f] = h_s[i][fb + f] + r2[f];

        float t1 = 0.f;
        #pragma unroll
        for (int f = 0; f < 64; ++f) t1 += x[f];
        t1 += __shfl_xor(t1, 1);
        const float mean2 = t1 * (1.f / 128.f);
        float t2 = 0.f;
        #pragma unroll
        for (int f = 0; f < 64; ++f) { float d = x[f] - mean2; t2 += d * d; }
        t2 += __shfl_xor(t2, 1);
        const float rstd2 = rsqrtf(t2 * (1.f / 128.f) + 1e-5f);
        const float* g2  = ln2_g + l * HID;
        const float* bb2 = ln2_b + l * HID;
        #pragma unroll
        for (int f = 0; f < 64; ++f)
            h_s[i][fb + f] = (x[f] - mean2) * rstd2 * g2[fb + f] + bb2[fb + f];
        __syncthreads();
    }

    // ---------------- pool over seq ----------------------------------------
    if (tid < 128) {
        float s = 0.f;
        for (int ii = 0; ii < 128; ++ii) s += h_s[ii][tid];
        pooled[b * HID + tid] = s * (1.f / 128.f);
    }
}

// ============================================================
// P6: final mean over neighbors + prediction head
// ============================================================
__global__ void final_pred(const float* __restrict__ pooled,
                           const float* __restrict__ w1, const float* __restrict__ b1,
                           const float* __restrict__ w2, const float* __restrict__ b2,
                           float* __restrict__ out)
{
    __shared__ float fin[HID];
    __shared__ float hm[HID];
    const int tid = threadIdx.x;   // 128
    float s = 0.f;
    for (int bb = 0; bb < D_N; ++bb) s += pooled[bb * HID + tid];
    fin[tid] = s * (1.f / (float)D_N);
    __syncthreads();
    float a = b1[tid];
    for (int f = 0; f < HID; ++f) a += fin[f] * w1[tid * HID + f];
    hm[tid] = fmaxf(a, 0.f) * w2[tid];
    __syncthreads();
    if (tid == 0) {
        float z = 0.f;
        for (int j = 0; j < HID; ++j) z += hm[j];
        z += b2[0];
        out[0] = 1.f / (1.f + __expf(-z));
    }
}

// ============================================================
// launch
// ============================================================
extern "C" void kernel_launch(void* const* d_in, const int* in_sizes, int n_in,
                              void* d_out, int out_size, void* d_ws, size_t ws_size,
                              hipStream_t stream)
{
    (void)in_sizes; (void)n_in; (void)out_size; (void)ws_size;

    const int*   tgt    = (const int*)  d_in[0];
    const int*   eidx   = (const int*)  d_in[2];
    const float* eattr  = (const float*)d_in[3];
    const float* ftm    = (const float*)d_in[4];
    const float* projw  = (const float*)d_in[5];
    const float* projb  = (const float*)d_in[6];
    const float* aiw    = (const float*)d_in[7];
    const float* aib    = (const float*)d_in[8];
    const float* aow    = (const float*)d_in[9];
    const float* aob    = (const float*)d_in[10];
    const float* l1g    = (const float*)d_in[11];
    const float* l1b    = (const float*)d_in[12];
    const float* f1w    = (const float*)d_in[13];
    const float* f1b    = (const float*)d_in[14];
    const float* f2w    = (const float*)d_in[15];
    const float* f2b    = (const float*)d_in[16];
    const float* l2g    = (const float*)d_in[17];
    const float* l2b    = (const float*)d_in[18];
    const float* pw1    = (const float*)d_in[19];
    const float* pb1    = (const float*)d_in[20];
    const float* pw2    = (const float*)d_in[21];
    const float* pb2    = (const float*)d_in[22];

    char* ws = (char*)d_ws;
    int*   order  = (int*)  (ws + OFF_ORDER);
    int*   key    = (int*)  (ws + OFF_KEY);
    int*   slot   = (int*)  (ws + OFF_SLOT);
    int*   hist   = (int*)  (ws + OFF_HIST);
    float* pooled = (float*)(ws + OFF_POOL);

    init_ws        <<<dim3(1024), dim3(256),  0, stream>>>(slot, hist);
    find_neigh     <<<dim3(1),    dim3(1024), 0, stream>>>(eidx, tgt, slot);
    hist_build     <<<dim3(2),    dim3(256),  0, stream>>>(eidx, tgt, slot, key, hist);
    scan_hist      <<<dim3(1),    dim3(1024), 0, stream>>>(hist);
    scatter_order  <<<dim3(2),    dim3(256),  0, stream>>>(key, hist, order);
    fused_transformer<<<dim3(D_N), dim3(256), 0, stream>>>(
        eattr, ftm, projw, projb, aiw, aib, aow, aob,
        l1g, l1b, f1w, f1b, f2w, f2b, l2g, l2b, order, pooled);
    final_pred     <<<dim3(1),    dim3(128),  0, stream>>>(pooled, pw1, pb1, pw2, pb2, (float*)d_out);
}

// Round 2
// 916.693 us; speedup vs baseline: 9.4468x; 9.4468x over previous
//
#include <hip/hip_runtime.h>
#include <cstdint>
#include <cstddef>

// ---------------- problem constants ----------------
#define D_N     1024
#define K_S     128
#define EDIM    384
#define HID     128
#define NHEAD   4
#define HDIM    32
#define FFD     128
#define NLAYER  2
#define ETOT    (D_N * K_S)
#define NNODES  200000
#define NBINS   (2 * D_N + 2)
#define NCH     512
#define CHL     (ETOT / NCH)

// ---------------- workspace layout (bytes) ----------------
#define OFF_ORDER 0u
#define OFF_KEY   (1u << 19)
#define OFF_SLOT  (1u << 20)
#define OFF_HIST  (1u << 21)               // 2050*512*4 = 4,198,400
#define OFF_TOT   (OFF_HIST + NBINS * NCH * 4)   // 8200 B
#define OFF_POOL  (7u << 20)
// bf16 weights overwrite the hist region AFTER the sort is done:
#define OFF_WBF   OFF_HIST
#define WP_OFF 0
#define WI_OFF 49152
#define WO_OFF 147456
#define W1_OFF 180224
#define W2_OFF 212992

typedef __attribute__((ext_vector_type(8))) short  bf16x8;
typedef __attribute__((ext_vector_type(4))) short  short4v;
typedef __attribute__((ext_vector_type(4))) float  f32x4;

__device__ __forceinline__ short f2bf(float f) {
    union { float f; unsigned u; } v; v.f = f;
    unsigned r = v.u + 0x7fffu + ((v.u >> 16) & 1u);
    return (short)(r >> 16);
}
// XOR swizzle: bijective, spreads row-strided reads across banks (T2)
__device__ __forceinline__ int swz_off(int r, int byteInRow, int strideBytes) {
    return (r * strideBytes + byteInRow) ^ ((r & 7) << 4);
}

// ============================================================
// preprocessing (stable counting sort of edges by (slot,is_tgt))
// ============================================================
__global__ void init_ws(int* __restrict__ slot, int* __restrict__ hist)
{
    int idx = blockIdx.x * blockDim.x + threadIdx.x;
    int stride = gridDim.x * blockDim.x;
    for (int i = idx; i < NBINS * NCH; i += stride) hist[i] = 0;
    for (int i = idx; i < NNODES; i += stride) slot[i] = D_N;
}

__global__ void find_neigh(const int* __restrict__ eidx,
                           const int* __restrict__ tgt_idx,
                           int* __restrict__ slot)
{
    __shared__ int cnt[1024];
    __shared__ int neigh[D_N];
    const int tid = threadIdx.x;
    const int tgt = tgt_idx[0];
    const int* src = eidx;
    const int* dst = eidx + ETOT;
    const int epc = ETOT / 1024;
    const int e0 = tid * epc;

    int c = 0;
    for (int e = e0; e < e0 + epc; ++e) c += (src[e] == tgt) ? 1 : 0;
    cnt[tid] = c;
    __syncthreads();
    for (int s = 1; s < 1024; s <<= 1) {
        int add = (tid >= s) ? cnt[tid - s] : 0;
        __syncthreads();
        cnt[tid] += add;
        __syncthreads();
    }
    int r = cnt[tid] - c;
    for (int e = e0; e < e0 + epc; ++e) {
        if (src[e] == tgt) { if (r < D_N) neigh[r] = dst[e]; ++r; }
    }
    __syncthreads();
    int total = cnt[1023];
    if (tid < total && tid < D_N) slot[neigh[tid]] = tid;
}

__global__ void hist_build(const int* __restrict__ eidx,
                           const int* __restrict__ tgt_idx,
                           const int* __restrict__ slot,
                           int* __restrict__ key,
                           int* __restrict__ hist)
{
    const int c = blockIdx.x * blockDim.x + threadIdx.x;
    if (c >= NCH) return;
    const int tgt = tgt_idx[0];
    const int* src = eidx;
    const int* dst = eidx + ETOT;
    const int e0 = c * CHL;
    int cur = -1, run = 0;
    for (int e = e0; e < e0 + CHL; ++e) {
        int k = slot[dst[e]] * 2 + ((src[e] != tgt) ? 1 : 0);
        key[e] = k;
        if (k == cur) { ++run; }
        else {
            if (run) hist[cur * NCH + c] += run;
            cur = k; run = 1;
        }
    }
    if (run) hist[cur * NCH + c] += run;
}

__global__ void scan_pass1(const int* __restrict__ hist, int* __restrict__ tot)
{
    int b = blockIdx.x * 256 + threadIdx.x;
    if (b >= NBINS) return;
    const int* h = hist + b * NCH;
    int s = 0;
    #pragma unroll 8
    for (int c = 0; c < NCH; ++c) s += h[c];
    tot[b] = s;
}

#define SCN 2176
__global__ void scan_pass2(int* __restrict__ tot)
{
    __shared__ int A[SCN];
    __shared__ int B[SCN];
    const int tid = threadIdx.x;   // 1024
    for (int i = tid; i < SCN; i += 1024) A[i] = (i < NBINS) ? tot[i] : 0;
    __syncthreads();
    int* cur = A; int* nxt = B;
    for (int s = 1; s < SCN; s <<= 1) {
        for (int i = tid; i < SCN; i += 1024) nxt[i] = (i >= s) ? cur[i] + cur[i - s] : cur[i];
        __syncthreads();
        int* t = cur; cur = nxt; nxt = t;
    }
    for (int i = tid; i < NBINS; i += 1024) tot[i] = (i == 0) ? 0 : cur[i - 1];
}

__global__ void scan_pass3(int* __restrict__ hist, const int* __restrict__ base)
{
    int b = blockIdx.x * 256 + threadIdx.x;
    if (b >= NBINS) return;
    int run = base[b];
    int* h = hist + b * NCH;
    for (int c = 0; c < NCH; ++c) { int t = h[c]; h[c] = run; run += t; }
}

__global__ void scatter_order(const int* __restrict__ key,
                              int* __restrict__ hist,
                              int* __restrict__ order)
{
    const int c = blockIdx.x * blockDim.x + threadIdx.x;
    if (c >= NCH) return;
    const int e0 = c * CHL;
    int cur = -1, pos = 0;
    for (int e = e0; e < e0 + CHL; ++e) {
        int k = key[e];
        if (k != cur) {
            if (cur >= 0) hist[cur * NCH + c] = pos;
            cur = k;
            pos = hist[k * NCH + c];
        }
        if (pos >= 0 && pos < ETOT) order[pos] = e;
        ++pos;
    }
    if (cur >= 0) hist[cur * NCH + c] = pos;
}

// fp32 -> bf16 weight conversion (vectorized by 4)
__global__ void cvt_w(const float* __restrict__ s, short* __restrict__ d, int n4)
{
    int i = (blockIdx.x * 256 + threadIdx.x);
    if (i >= n4) return;
    float4 v = *(const float4*)(s + i * 4);
    short4v p;
    p[0] = f2bf(v.x); p[1] = f2bf(v.y); p[2] = f2bf(v.z); p[3] = f2bf(v.w);
    *(short4v*)(d + i * 4) = p;
}

// ============================================================
// MFMA tile GEMM: A from (swizzled) LDS, B via functor.
// C fragment mapping: col = l15+16*cf, row = row0 + rf*16 + g*4 + reg.
// ============================================================
template<int RF, int CF, int KC, typename GetB>
__device__ __forceinline__ void gemm(f32x4 (&acc)[RF][CF],
    const char* aB, int aRow0, int aStride, int l15, int g, GetB getB)
{
    #pragma unroll
    for (int kc = 0; kc < KC; ++kc) {
        bf16x8 a[RF];
        #pragma unroll
        for (int rf = 0; rf < RF; ++rf)
            a[rf] = *(const bf16x8*)(aB + swz_off(aRow0 + rf * 16 + l15, kc * 64 + g * 16, aStride));
        #pragma unroll
        for (int cf = 0; cf < CF; ++cf) {
            bf16x8 bfr = getB(cf, kc);
            #pragma unroll
            for (int rf = 0; rf < RF; ++rf)
                acc[rf][cf] = __builtin_amdgcn_mfma_f32_16x16x32_bf16(a[rf], bfr, acc[rf][cf], 0, 0, 0);
        }
    }
}

__device__ __forceinline__ void layer_norm(f32x4 (&x)[2][8],
    const float* __restrict__ gg, const float* __restrict__ bb, int l15)
{
    float gv[8], bv[8];
    #pragma unroll
    for (int cf = 0; cf < 8; ++cf) { gv[cf] = gg[l15 + 16 * cf]; bv[cf] = bb[l15 + 16 * cf]; }
    #pragma unroll
    for (int rf = 0; rf < 2; ++rf) {
        #pragma unroll
        for (int rg = 0; rg < 4; ++rg) {
            float s = 0.f;
            #pragma unroll
            for (int cf = 0; cf < 8; ++cf) s += x[rf][cf][rg];
            s += __shfl_xor(s, 1); s += __shfl_xor(s, 2);
            s += __shfl_xor(s, 4); s += __shfl_xor(s, 8);
            float mean = s * (1.f / 128.f);
            float v = 0.f;
            #pragma unroll
            for (int cf = 0; cf < 8; ++cf) { float d = x[rf][cf][rg] - mean; v += d * d; }
            v += __shfl_xor(v, 1); v += __shfl_xor(v, 2);
            v += __shfl_xor(v, 4); v += __shfl_xor(v, 8);
            float rs = rsqrtf(v * (1.f / 128.f) + 1e-5f);
            #pragma unroll
            for (int cf = 0; cf < 8; ++cf)
                x[rf][cf][rg] = (x[rf][cf][rg] - mean) * rs * gv[cf] + bv[cf];
        }
    }
}

// ============================================================
// fused per-neighbor transformer, MFMA version.
// 1 block = 1 neighbor. 4 waves; wave w owns token rows 32w..32w+31.
// Residual stream lives in registers as C-fragments (f32x4[2][8]).
// ============================================================
#define LDS_TOTAL 133120
__global__ __launch_bounds__(256, 1) void fused_mfma(
    const float* __restrict__ edge_attrs,
    const float* __restrict__ ftm,
    const short* __restrict__ wP, const float* __restrict__ projb,
    const short* __restrict__ wI, const float* __restrict__ aib,
    const short* __restrict__ wO, const float* __restrict__ aob,
    const float* __restrict__ l1g, const float* __restrict__ l1b,
    const short* __restrict__ w1, const float* __restrict__ f1b,
    const short* __restrict__ w2, const float* __restrict__ f2b,
    const float* __restrict__ l2g, const float* __restrict__ l2b,
    const int*   __restrict__ order,
    float*       __restrict__ pooled)
{
    __shared__ __align__(16) char sm[LDS_TOTAL];
    char* hbf  = sm;                    // [128][128] bf16 swz, stride 256
    char* regA = sm + 32768;            // union region (98304 B)
    // proj phase: ebuf = regA, [128][384] bf16, stride 768
    char* ebuf = regA;
    // layer phase:
    char* q_l  = regA;                  // [128][32]  bf16, stride 64
    char* k_l  = regA + 8192;           // [128][32]
    char* vT   = regA + 16384;          // [32][128]  (dim-major), stride 256
    char* P_l  = regA + 24576;          // [128][128] stride 256 (also ffbuf)
    char* o_l  = regA + 57344;          // [128][128] stride 256
    float* pool_s = (float*)(sm + 131072); // [4][128] f32

    const int tid  = threadIdx.x;
    const int w    = tid >> 6;
    const int l    = tid & 63;
    const int l15  = l & 15;
    const int g    = l >> 4;
    const int row0 = 32 * w;
    const int b    = blockIdx.x;

    // ---- stage this wave's 32 edge rows as bf16 into ebuf (wave-local) ----
    {
        const int r    = row0 + ((tid & 63) >> 1);
        const int half = tid & 1;
        const int rowIdx = order[b * K_S + r];
        const float* src = edge_attrs + (size_t)rowIdx * EDIM + half * 192;
        #pragma unroll
        for (int c = 0; c < 192; c += 8) {
            float4 v0 = *(const float4*)(src + c);
            float4 v1 = *(const float4*)(src + c + 4);
            bf16x8 pk;
            pk[0] = f2bf(v0.x); pk[1] = f2bf(v0.y); pk[2] = f2bf(v0.z); pk[3] = f2bf(v0.w);
            pk[4] = f2bf(v1.x); pk[5] = f2bf(v1.y); pk[6] = f2bf(v1.z); pk[7] = f2bf(v1.w);
            *(bf16x8*)(ebuf + swz_off(r, (half * 192 + c) * 2, 768)) = pk;
        }
    }

    f32x4 h_res[2][8];

    // ---- proj: h = rows @ projW^T + b (+ marker on token 0) ----
    {
        f32x4 acc[2][8];
        #pragma unroll
        for (int cf = 0; cf < 8; ++cf) {
            float bs = projb[l15 + 16 * cf];
            acc[0][cf] = (f32x4){bs, bs, bs, bs};
            acc[1][cf] = acc[0][cf];
        }
        gemm<2, 8, 12>(acc, ebuf, row0, 768, l15, g,
            [&](int cf, int kc) {
                int col = l15 + 16 * cf;
                return *(const bf16x8*)(wP + (size_t)col * EDIM + kc * 32 + g * 8);
            });
        if (w == 0 && g == 0) {
            #pragma unroll
            for (int cf = 0; cf < 8; ++cf) acc[0][cf][0] += ftm[l15 + 16 * cf];
        }
        #pragma unroll
        for (int rf = 0; rf < 2; ++rf)
            #pragma unroll
            for (int cf = 0; cf < 8; ++cf) {
                h_res[rf][cf] = acc[rf][cf];
                #pragma unroll
                for (int rg = 0; rg < 4; ++rg)
                    *(short*)(hbf + swz_off(row0 + rf * 16 + g * 4 + rg,
                                            (l15 + 16 * cf) * 2, 256)) = f2bf(acc[rf][cf][rg]);
            }
    }

    // ---- transformer layers ----
    for (int ly = 0; ly < NLAYER; ++ly) {
        const short* WIl = wI + (size_t)ly * 3 * HID * HID;
        const float* bI  = aib + ly * 3 * HID;
        const short* WOl = wO + (size_t)ly * HID * HID;
        const float* bO  = aob + ly * HID;
        const short* W1l = w1 + (size_t)ly * FFD * HID;
        const float* b1  = f1b + ly * FFD;
        const short* W2l = w2 + (size_t)ly * HID * FFD;
        const float* b2v = f2b + ly * HID;

        for (int hd = 0; hd < NHEAD; ++hd) {
            // per-head QKV GEMM (N = 96: q|k|v each 32)
            f32x4 acc[2][6];
            #pragma unroll
            for (int cf = 0; cf < 6; ++cf) {
                int sec = cf >> 1;
                float bs = bI[sec * HID + hd * HDIM + l15 + 16 * (cf & 1)];
                acc[0][cf] = (f32x4){bs, bs, bs, bs};
                acc[1][cf] = acc[0][cf];
            }
            gemm<2, 6, 4>(acc, hbf, row0, 256, l15, g,
                [&](int cf, int kc) {
                    int sec = cf >> 1;
                    int colw = sec * HID + hd * HDIM + l15 + 16 * (cf & 1);
                    return *(const bf16x8*)(WIl + (size_t)colw * HID + kc * 32 + g * 8);
                });
            // store q,k (token-major) and v (dim-major, packed b64)
            #pragma unroll
            for (int rf = 0; rf < 2; ++rf)
                #pragma unroll
                for (int cf = 0; cf < 2; ++cf) {
                    int dcol = (l15 + 16 * cf) * 2;
                    #pragma unroll
                    for (int rg = 0; rg < 4; ++rg) {
                        int row = row0 + rf * 16 + g * 4 + rg;
                        *(short*)(q_l + swz_off(row, dcol, 64)) = f2bf(acc[rf][cf][rg]);
                        *(short*)(k_l + swz_off(row, dcol, 64)) = f2bf(acc[rf][2 + cf][rg]);
                    }
                    short4v pv;
                    pv[0] = f2bf(acc[rf][4 + cf][0]); pv[1] = f2bf(acc[rf][4 + cf][1]);
                    pv[2] = f2bf(acc[rf][4 + cf][2]); pv[3] = f2bf(acc[rf][4 + cf][3]);
                    *(short4v*)(vT + swz_off(l15 + 16 * cf, (row0 + rf * 16 + g * 4) * 2, 256)) = pv;
                }
            __syncthreads();

            // S = Q @ K^T  (M = own 32 q rows, N = 128 ktok, K = 32)
            f32x4 sc[2][8];
            #pragma unroll
            for (int rf = 0; rf < 2; ++rf)
                #pragma unroll
                for (int cf = 0; cf < 8; ++cf) sc[rf][cf] = (f32x4){0.f, 0.f, 0.f, 0.f};
            gemm<2, 8, 1>(sc, q_l, row0, 64, l15, g,
                [&](int cf, int kc) {
                    (void)kc;
                    return *(const bf16x8*)(k_l + swz_off(l15 + 16 * cf, g * 16, 64));
                });

            // softmax over ktok (per q-row: 8 regs local + 4 shfl_xor)
            const float SC_ = 0.17677669529663687f;   // 1/sqrt(32)
            #pragma unroll
            for (int rf = 0; rf < 2; ++rf) {
                #pragma unroll
                for (int rg = 0; rg < 4; ++rg) {
                    float mx = -1e30f;
                    #pragma unroll
                    for (int cf = 0; cf < 8; ++cf) {
                        sc[rf][cf][rg] *= SC_;
                        mx = fmaxf(mx, sc[rf][cf][rg]);
                    }
                    mx = fmaxf(mx, __shfl_xor(mx, 1)); mx = fmaxf(mx, __shfl_xor(mx, 2));
                    mx = fmaxf(mx, __shfl_xor(mx, 4)); mx = fmaxf(mx, __shfl_xor(mx, 8));
                    float sum = 0.f;
                    #pragma unroll
                    for (int cf = 0; cf < 8; ++cf) {
                        float e = __expf(sc[rf][cf][rg] - mx);
                        sc[rf][cf][rg] = e; sum += e;
                    }
                    sum += __shfl_xor(sum, 1); sum += __shfl_xor(sum, 2);
                    sum += __shfl_xor(sum, 4); sum += __shfl_xor(sum, 8);
                    float inv = 1.f / sum;
                    int row = row0 + rf * 16 + g * 4 + rg;
                    #pragma unroll
                    for (int cf = 0; cf < 8; ++cf)
                        *(short*)(P_l + swz_off(row, (l15 + 16 * cf) * 2, 256)) =
                            f2bf(sc[rf][cf][rg] * inv);
                }
            }

            // O = P @ V  (N = 32 dims, K = 128 ktok)
            f32x4 ov[2][2];
            #pragma unroll
            for (int rf = 0; rf < 2; ++rf) { ov[rf][0] = (f32x4){0,0,0,0}; ov[rf][1] = (f32x4){0,0,0,0}; }
            gemm<2, 2, 4>(ov, P_l, row0, 256, l15, g,
                [&](int cf, int kc) {
                    return *(const bf16x8*)(vT + swz_off(l15 + 16 * cf, kc * 64 + g * 16, 256));
                });
            #pragma unroll
            for (int rf = 0; rf < 2; ++rf)
                #pragma unroll
                for (int cf = 0; cf < 2; ++cf)
                    #pragma unroll
                    for (int rg = 0; rg < 4; ++rg)
                        *(short*)(o_l + swz_off(row0 + rf * 16 + g * 4 + rg,
                                                (hd * HDIM + l15 + 16 * cf) * 2, 256)) =
                            f2bf(ov[rf][cf][rg]);
            __syncthreads();
        } // heads

        // out-proj + residual + LN1
        f32x4 xx[2][8];
        #pragma unroll
        for (int cf = 0; cf < 8; ++cf) {
            float bs = bO[l15 + 16 * cf];
            xx[0][cf] = (f32x4){bs, bs, bs, bs};
            xx[1][cf] = xx[0][cf];
        }
        gemm<2, 8, 4>(xx, o_l, row0, 256, l15, g,
            [&](int cf, int kc) {
                int col = l15 + 16 * cf;
                return *(const bf16x8*)(WOl + (size_t)col * HID + kc * 32 + g * 8);
            });
        #pragma unroll
        for (int rf = 0; rf < 2; ++rf)
            #pragma unroll
            for (int cf = 0; cf < 8; ++cf) xx[rf][cf] += h_res[rf][cf];
        layer_norm(xx, l1g + ly * HID, l1b + ly * HID, l15);
        #pragma unroll
        for (int rf = 0; rf < 2; ++rf)
            #pragma unroll
            for (int cf = 0; cf < 8; ++cf) {
                h_res[rf][cf] = xx[rf][cf];
                #pragma unroll
                for (int rg = 0; rg < 4; ++rg)
                    *(short*)(hbf + swz_off(row0 + rf * 16 + g * 4 + rg,
                                            (l15 + 16 * cf) * 2, 256)) = f2bf(xx[rf][cf][rg]);
            }

        // FF1 (relu) -> ffbuf (=P_l)
        f32x4 ff[2][8];
        #pragma unroll
        for (int cf = 0; cf < 8; ++cf) {
            float bs = b1[l15 + 16 * cf];
            ff[0][cf] = (f32x4){bs, bs, bs, bs};
            ff[1][cf] = ff[0][cf];
        }
        gemm<2, 8, 4>(ff, hbf, row0, 256, l15, g,
            [&](int cf, int kc) {
                int col = l15 + 16 * cf;
                return *(const bf16x8*)(W1l + (size_t)col * HID + kc * 32 + g * 8);
            });
        #pragma unroll
        for (int rf = 0; rf < 2; ++rf)
            #pragma unroll
            for (int cf = 0; cf < 8; ++cf)
                #pragma unroll
                for (int rg = 0; rg < 4; ++rg)
                    *(short*)(P_l + swz_off(row0 + rf * 16 + g * 4 + rg,
                                            (l15 + 16 * cf) * 2, 256)) =
                        f2bf(fmaxf(ff[rf][cf][rg], 0.f));

        // FF2 + residual + LN2
        f32x4 yy[2][8];
        #pragma unroll
        for (int cf = 0; cf < 8; ++cf) {
            float bs = b2v[l15 + 16 * cf];
            yy[0][cf] = (f32x4){bs, bs, bs, bs};
            yy[1][cf] = yy[0][cf];
        }
        gemm<2, 8, 4>(yy, P_l, row0, 256, l15, g,
            [&](int cf, int kc) {
                int col = l15 + 16 * cf;
                return *(const bf16x8*)(W2l + (size_t)col * FFD + kc * 32 + g * 8);
            });
        #pragma unroll
        for (int rf = 0; rf < 2; ++rf)
            #pragma unroll
            for (int cf = 0; cf < 8; ++cf) yy[rf][cf] += h_res[rf][cf];
        layer_norm(yy, l2g + ly * HID, l2b + ly * HID, l15);
        #pragma unroll
        for (int rf = 0; rf < 2; ++rf)
            #pragma unroll
            for (int cf = 0; cf < 8; ++cf) {
                h_res[rf][cf] = yy[rf][cf];
                #pragma unroll
                for (int rg = 0; rg < 4; ++rg)
                    *(short*)(hbf + swz_off(row0 + rf * 16 + g * 4 + rg,
                                            (l15 + 16 * cf) * 2, 256)) = f2bf(yy[rf][cf][rg]);
            }
    } // layers

    // ---- pool over the 128 tokens ----
    #pragma unroll
    for (int cf = 0; cf < 8; ++cf) {
        float s = 0.f;
        #pragma unroll
        for (int rf = 0; rf < 2; ++rf)
            #pragma unroll
            for (int rg = 0; rg < 4; ++rg) s += h_res[rf][cf][rg];
        s += __shfl_xor(s, 16); s += __shfl_xor(s, 32);
        if (g == 0) pool_s[w * 128 + l15 + 16 * cf] = s;
    }
    __syncthreads();
    if (tid < 128) {
        float s = pool_s[tid] + pool_s[128 + tid] + pool_s[256 + tid] + pool_s[384 + tid];
        pooled[b * HID + tid] = s * (1.f / 128.f);
    }
}

// ============================================================
// final mean over neighbors + prediction head
// ============================================================
__global__ void final_pred(const float* __restrict__ pooled,
                           const float* __restrict__ w1, const float* __restrict__ b1,
                           const float* __restrict__ w2, const float* __restrict__ b2,
                           float* __restrict__ out)
{
    __shared__ float fin[HID];
    __shared__ float hm[HID];
    const int tid = threadIdx.x;   // 128
    float s = 0.f;
    for (int bb = 0; bb < D_N; ++bb) s += pooled[bb * HID + tid];
    fin[tid] = s * (1.f / (float)D_N);
    __syncthreads();
    float a = b1[tid];
    for (int f = 0; f < HID; ++f) a += fin[f] * w1[tid * HID + f];
    hm[tid] = fmaxf(a, 0.f) * w2[tid];
    __syncthreads();
    if (tid == 0) {
        float z = 0.f;
        for (int j = 0; j < HID; ++j) z += hm[j];
        z += b2[0];
        out[0] = 1.f / (1.f + __expf(-z));
    }
}

// ============================================================
// launch
// ============================================================
extern "C" void kernel_launch(void* const* d_in, const int* in_sizes, int n_in,
                              void* d_out, int out_size, void* d_ws, size_t ws_size,
                              hipStream_t stream)
{
    (void)in_sizes; (void)n_in; (void)out_size; (void)ws_size;

    const int*   tgt   = (const int*)  d_in[0];
    const int*   eidx  = (const int*)  d_in[2];
    const float* eattr = (const float*)d_in[3];
    const float* ftm   = (const float*)d_in[4];
    const float* projw = (const float*)d_in[5];
    const float* projb = (const float*)d_in[6];
    const float* aiw   = (const float*)d_in[7];
    const float* aib   = (const float*)d_in[8];
    const float* aow   = (const float*)d_in[9];
    const float* aob   = (const float*)d_in[10];
    const float* l1g   = (const float*)d_in[11];
    const float* l1b   = (const float*)d_in[12];
    const float* f1w   = (const float*)d_in[13];
    const float* f1b   = (const float*)d_in[14];
    const float* f2w   = (const float*)d_in[15];
    const float* f2b   = (const float*)d_in[16];
    const float* l2g   = (const float*)d_in[17];
    const float* l2b   = (const float*)d_in[18];
    const float* pw1   = (const float*)d_in[19];
    const float* pb1   = (const float*)d_in[20];
    const float* pw2   = (const float*)d_in[21];
    const float* pb2   = (const float*)d_in[22];

    char* ws = (char*)d_ws;
    int*   order  = (int*)  (ws + OFF_ORDER);
    int*   key    = (int*)  (ws + OFF_KEY);
    int*   slot   = (int*)  (ws + OFF_SLOT);
    int*   hist   = (int*)  (ws + OFF_HIST);
    int*   tot    = (int*)  (ws + OFF_TOT);
    float* pooled = (float*)(ws + OFF_POOL);
    short* wbf    = (short*)(ws + OFF_WBF);   // overwrites hist AFTER sort

    init_ws      <<<dim3(1024), dim3(256),  0, stream>>>(slot, hist);
    find_neigh   <<<dim3(1),    dim3(1024), 0, stream>>>(eidx, tgt, slot);
    hist_build   <<<dim3(8),    dim3(64),   0, stream>>>(eidx, tgt, slot, key, hist);
    scan_pass1   <<<dim3(9),    dim3(256),  0, stream>>>(hist, tot);
    scan_pass2   <<<dim3(1),    dim3(1024), 0, stream>>>(tot);
    scan_pass3   <<<dim3(9),    dim3(256),  0, stream>>>(hist, tot);
    scatter_order<<<dim3(8),    dim3(64),   0, stream>>>(key, hist, order);

    cvt_w<<<dim3(48), dim3(256), 0, stream>>>(projw, wbf + WP_OFF, 49152 / 4);
    cvt_w<<<dim3(96), dim3(256), 0, stream>>>(aiw,   wbf + WI_OFF, 98304 / 4);
    cvt_w<<<dim3(32), dim3(256), 0, stream>>>(aow,   wbf + WO_OFF, 32768 / 4);
    cvt_w<<<dim3(32), dim3(256), 0, stream>>>(f1w,   wbf + W1_OFF, 32768 / 4);
    cvt_w<<<dim3(32), dim3(256), 0, stream>>>(f2w,   wbf + W2_OFF, 32768 / 4);

    fused_mfma<<<dim3(D_N), dim3(256), 0, stream>>>(
        eattr, ftm,
        wbf + WP_OFF, projb,
        wbf + WI_OFF, aib,
        wbf + WO_OFF, aob,
        l1g, l1b,
        wbf + W1_OFF, f1b,
        wbf + W2_OFF, f2b,
        l2g, l2b,
        order, pooled);

    final_pred<<<dim3(1), dim3(128), 0, stream>>>(pooled, pw1, pb1, pw2, pb2, (float*)d_out);
}

// Round 3
// 843.049 us; speedup vs baseline: 10.2720x; 1.0874x over previous
//
#include <hip/hip_runtime.h>
#include <cstdint>
#include <cstddef>

// ---------------- problem constants ----------------
#define D_N     1024
#define K_S     128
#define EDIM    384
#define HID     128
#define NHEAD   4
#define HDIM    32
#define FFD     128
#define NLAYER  2
#define ETOT    (D_N * K_S)
#define NNODES  200000
#define NBINS   (2 * D_N + 2)
#define NCH     512
#define CHL     (ETOT / NCH)

// ---------------- workspace layout (bytes) ----------------
#define OFF_ORDER 0u
#define OFF_KEY   (1u << 19)
#define OFF_SLOT  (1u << 20)
#define OFF_HIST  (1u << 21)               // 2050*512*4 = 4,198,400
#define OFF_TOT   (OFF_HIST + NBINS * NCH * 4)
#define OFF_POOL  (7u << 20)
// bf16 weights overwrite hist AFTER the sort (stream-ordered):
#define OFF_WBF   OFF_HIST
#define WP_OFF 0
#define WI_OFF 49152
#define WO_OFF 147456
#define W1_OFF 180224
#define W2_OFF 212992
#define WTOT   245760

typedef __attribute__((ext_vector_type(8))) short  bf16x8;
typedef __attribute__((ext_vector_type(4))) short  short4v;
typedef __attribute__((ext_vector_type(4))) float  f32x4;

__device__ __forceinline__ short f2bf(float f) {
    union { float f; unsigned u; } v; v.f = f;
    unsigned r = v.u + 0x7fffu + ((v.u >> 16) & 1u);
    return (short)(r >> 16);
}
__device__ __forceinline__ int swz_off(int r, int byteInRow, int strideBytes) {
    return (r * strideBytes + byteInRow) ^ ((r & 7) << 4);
}

// ============================================================
// preprocessing
// ============================================================
__global__ void init_ws(int* __restrict__ slot, int* __restrict__ hist)
{
    int idx = blockIdx.x * blockDim.x + threadIdx.x;
    int stride = gridDim.x * blockDim.x;
    for (int i = idx; i < NBINS * NCH; i += stride) hist[i] = 0;
    for (int i = idx; i < NNODES; i += stride) slot[i] = D_N;
}

__global__ void find_neigh(const int* __restrict__ eidx,
                           const int* __restrict__ tgt_idx,
                           int* __restrict__ slot)
{
    __shared__ int cnt[1024];
    __shared__ int neigh[D_N];
    const int tid = threadIdx.x;
    const int tgt = tgt_idx[0];
    const int* src = eidx;
    const int* dst = eidx + ETOT;
    const int epc = ETOT / 1024;           // 128
    const int e0 = tid * epc;

    int c = 0;
    const int4* s4 = (const int4*)(src + e0);
    #pragma unroll 8
    for (int i = 0; i < epc / 4; ++i) {
        int4 v = s4[i];
        c += (v.x == tgt) + (v.y == tgt) + (v.z == tgt) + (v.w == tgt);
    }
    cnt[tid] = c;
    __syncthreads();
    for (int s = 1; s < 1024; s <<= 1) {
        int add = (tid >= s) ? cnt[tid - s] : 0;
        __syncthreads();
        cnt[tid] += add;
        __syncthreads();
    }
    int r = cnt[tid] - c;
    for (int e = e0; e < e0 + epc; ++e) {
        if (src[e] == tgt) { if (r < D_N) neigh[r] = dst[e]; ++r; }
    }
    __syncthreads();
    int total = cnt[1023];
    if (tid < total && tid < D_N) slot[neigh[tid]] = tid;
}

__global__ void compute_key(const int* __restrict__ eidx,
                            const int* __restrict__ tgt_idx,
                            const int* __restrict__ slot,
                            int* __restrict__ key)
{
    int e = blockIdx.x * 256 + threadIdx.x;
    if (e >= ETOT) return;
    int tgt = tgt_idx[0];
    key[e] = slot[eidx[ETOT + e]] * 2 + ((eidx[e] != tgt) ? 1 : 0);
}

__global__ void hist_build(const int* __restrict__ key, int* __restrict__ hist)
{
    const int c = blockIdx.x * 256 + threadIdx.x;
    if (c >= NCH) return;
    const int4* kp = (const int4*)(key + c * CHL);
    int cur = -1, run = 0;
    for (int i = 0; i < CHL / 4; ++i) {
        int4 k4 = kp[i];
        #pragma unroll
        for (int j = 0; j < 4; ++j) {
            int k = (j == 0) ? k4.x : (j == 1) ? k4.y : (j == 2) ? k4.z : k4.w;
            if (k == cur) { ++run; }
            else {
                if (run) hist[cur * NCH + c] += run;
                cur = k; run = 1;
            }
        }
    }
    if (run) hist[cur * NCH + c] += run;
}

__global__ void scan_pass1(const int* __restrict__ hist, int* __restrict__ tot)
{
    int b = blockIdx.x * 256 + threadIdx.x;
    if (b >= NBINS) return;
    const int4* h = (const int4*)(hist + b * NCH);
    int s = 0;
    #pragma unroll 4
    for (int c = 0; c < NCH / 4; ++c) { int4 v = h[c]; s += v.x + v.y + v.z + v.w; }
    tot[b] = s;
}

#define SCN 2176
__global__ void scan_pass2(int* __restrict__ tot)
{
    __shared__ int A[SCN];
    __shared__ int B[SCN];
    const int tid = threadIdx.x;   // 1024
    for (int i = tid; i < SCN; i += 1024) A[i] = (i < NBINS) ? tot[i] : 0;
    __syncthreads();
    int* cur = A; int* nxt = B;
    for (int s = 1; s < SCN; s <<= 1) {
        for (int i = tid; i < SCN; i += 1024) nxt[i] = (i >= s) ? cur[i] + cur[i - s] : cur[i];
        __syncthreads();
        int* t = cur; cur = nxt; nxt = t;
    }
    for (int i = tid; i < NBINS; i += 1024) tot[i] = (i == 0) ? 0 : cur[i - 1];
}

__global__ void scan_pass3(int* __restrict__ hist, const int* __restrict__ base)
{
    int b = blockIdx.x * 256 + threadIdx.x;
    if (b >= NBINS) return;
    int run = base[b];
    int4* h = (int4*)(hist + b * NCH);
    for (int i = 0; i < NCH / 4; ++i) {
        int4 v = h[i]; int4 o;
        o.x = run; run += v.x;
        o.y = run; run += v.y;
        o.z = run; run += v.z;
        o.w = run; run += v.w;
        h[i] = o;
    }
}

__global__ void scatter_order(const int* __restrict__ key,
                              int* __restrict__ hist,
                              int* __restrict__ order)
{
    const int c = blockIdx.x * 256 + threadIdx.x;
    if (c >= NCH) return;
    const int e0 = c * CHL;
    const int4* kp = (const int4*)(key + e0);
    int cur = -1, pos = 0;
    for (int i = 0; i < CHL / 4; ++i) {
        int4 k4 = kp[i];
        #pragma unroll
        for (int j = 0; j < 4; ++j) {
            int k = (j == 0) ? k4.x : (j == 1) ? k4.y : (j == 2) ? k4.z : k4.w;
            if (k != cur) {
                if (cur >= 0) hist[cur * NCH + c] = pos;
                cur = k;
                pos = hist[k * NCH + c];
            }
            if (pos >= 0 && pos < ETOT) order[pos] = e0 + i * 4 + j;
            ++pos;
        }
    }
    if (cur >= 0) hist[cur * NCH + c] = pos;
}

// all five weight blocks are contiguous in wbf
__global__ void cvt_all(const float* __restrict__ p0, const float* __restrict__ p1,
                        const float* __restrict__ p2, const float* __restrict__ p3,
                        const float* __restrict__ p4, short* __restrict__ wbf)
{
    int i = (blockIdx.x * 256 + threadIdx.x) * 8;
    if (i >= WTOT) return;
    const float* s;
    if      (i < WI_OFF) s = p0 + i;
    else if (i < WO_OFF) s = p1 + (i - WI_OFF);
    else if (i < W1_OFF) s = p2 + (i - WO_OFF);
    else if (i < W2_OFF) s = p3 + (i - W1_OFF);
    else                 s = p4 + (i - W2_OFF);
    float4 a = *(const float4*)s;
    float4 b = *(const float4*)(s + 4);
    bf16x8 o;
    o[0] = f2bf(a.x); o[1] = f2bf(a.y); o[2] = f2bf(a.z); o[3] = f2bf(a.w);
    o[4] = f2bf(b.x); o[5] = f2bf(b.y); o[6] = f2bf(b.z); o[7] = f2bf(b.w);
    *(bf16x8*)(wbf + i) = o;
}

// ============================================================
// MFMA helpers (RF = 1: wave owns 16 token rows)
// ============================================================
template<int CF, int KC, typename GetB>
__device__ __forceinline__ void gemm1(f32x4 (&acc)[CF],
    const char* aB, int aRow0, int aStride, int l15, int g, GetB getB)
{
    #pragma unroll
    for (int kc = 0; kc < KC; ++kc) {
        bf16x8 a = *(const bf16x8*)(aB + swz_off(aRow0 + l15, kc * 64 + g * 16, aStride));
        #pragma unroll
        for (int cf = 0; cf < CF; ++cf)
            acc[cf] = __builtin_amdgcn_mfma_f32_16x16x32_bf16(a, getB(cf, kc), acc[cf], 0, 0, 0);
    }
}

__device__ __forceinline__ void layer_norm1(f32x4 (&x)[8],
    const float* __restrict__ gg, const float* __restrict__ bb, int l15)
{
    float gv[8], bv[8];
    #pragma unroll
    for (int cf = 0; cf < 8; ++cf) { gv[cf] = gg[l15 + 16 * cf]; bv[cf] = bb[l15 + 16 * cf]; }
    #pragma unroll
    for (int rg = 0; rg < 4; ++rg) {
        float s = 0.f;
        #pragma unroll
        for (int cf = 0; cf < 8; ++cf) s += x[cf][rg];
        s += __shfl_xor(s, 1); s += __shfl_xor(s, 2);
        s += __shfl_xor(s, 4); s += __shfl_xor(s, 8);
        float mean = s * (1.f / 128.f);
        float v = 0.f;
        #pragma unroll
        for (int cf = 0; cf < 8; ++cf) { float d = x[cf][rg] - mean; v += d * d; }
        v += __shfl_xor(v, 1); v += __shfl_xor(v, 2);
        v += __shfl_xor(v, 4); v += __shfl_xor(v, 8);
        float rs = rsqrtf(v * (1.f / 128.f) + 1e-5f);
        #pragma unroll
        for (int cf = 0; cf < 8; ++cf)
            x[cf][rg] = (x[cf][rg] - mean) * rs * gv[cf] + bv[cf];
    }
}

// ============================================================
// fused transformer: 1 block = 1 neighbor; 512 thr = 8 waves x 16 rows.
// LDS exactly 64 KB -> 2 blocks/CU -> 4 waves/SIMD.
// ============================================================
#define LDS_TOTAL 65536
__global__ __launch_bounds__(512, 4) void fused_mfma(
    const float* __restrict__ edge_attrs,
    const float* __restrict__ ftm,
    const short* __restrict__ wP, const float* __restrict__ projb,
    const short* __restrict__ wI, const float* __restrict__ aib,
    const short* __restrict__ wO, const float* __restrict__ aob,
    const float* __restrict__ l1g, const float* __restrict__ l1b,
    const short* __restrict__ w1, const float* __restrict__ f1b,
    const short* __restrict__ w2, const float* __restrict__ f2b,
    const float* __restrict__ l2g, const float* __restrict__ l2b,
    const int*   __restrict__ order,
    float*       __restrict__ pooled)
{
    __shared__ __align__(16) char sm[LDS_TOTAL];
    char* hbf = sm;                         // [128 tok][128 feat] bf16 swz s256
    char* scr = sm + 32768;                 // 32 KB multi-purpose
    char* k_l  = scr;                       // [128][32] s64          (x-wave)
    char* vT   = scr + 8192;                // [32 dim][128 tok] s256 (x-wave)
    char* qOh  = scr + 16384;               // [128][32] s64  q then O_head (wave-local)
    char* Pch  = scr + 24576;               // [128][32] s64  P chunk (wave-local)
    char* ebuf = scr;                       // [128][128] s256 proj staging (wave-local)
    char* ffb  = scr;                       // [128][128] s256 ff1 staging (wave-local)
    float* pool_s = (float*)scr;            // [8][128] f32 (after final barrier)

    const int tid  = threadIdx.x;
    const int w    = tid >> 6;              // 0..7
    const int l    = tid & 63;
    const int l15  = l & 15;
    const int g    = l >> 4;
    const int row0 = 16 * w;
    const int b    = blockIdx.x;

    f32x4 hx[8];

    // ---------------- proj (EDIM = 3 x 128 chunks, all wave-local) --------
    {
        #pragma unroll
        for (int cf = 0; cf < 8; ++cf) {
            float bs = projb[l15 + 16 * cf];
            hx[cf] = (f32x4){bs, bs, bs, bs};
        }
        const int r_off = l >> 2;           // 0..15
        const int coff  = (l & 3) * 32;
        const int row   = row0 + r_off;
        const int rowIdx = order[b * K_S + row];
        const float* arow = edge_attrs + (size_t)rowIdx * EDIM;

        for (int ch = 0; ch < 3; ++ch) {
            #pragma unroll
            for (int j = 0; j < 4; ++j) {
                float4 v0 = *(const float4*)(arow + ch * 128 + coff + j * 8);
                float4 v1 = *(const float4*)(arow + ch * 128 + coff + j * 8 + 4);
                bf16x8 pk;
                pk[0] = f2bf(v0.x); pk[1] = f2bf(v0.y); pk[2] = f2bf(v0.z); pk[3] = f2bf(v0.w);
                pk[4] = f2bf(v1.x); pk[5] = f2bf(v1.y); pk[6] = f2bf(v1.z); pk[7] = f2bf(v1.w);
                *(bf16x8*)(ebuf + swz_off(row, coff * 2 + j * 16, 256)) = pk;
            }
            gemm1<8, 4>(hx, ebuf, row0, 256, l15, g,
                [&](int cf, int kc) {
                    int col = l15 + 16 * cf;
                    return *(const bf16x8*)(wP + (size_t)col * EDIM + ch * 128 + kc * 32 + g * 8);
                });
        }
        if (w == 0 && g == 0) {
            #pragma unroll
            for (int cf = 0; cf < 8; ++cf) hx[cf][0] += ftm[l15 + 16 * cf];
        }
        #pragma unroll
        for (int cf = 0; cf < 8; ++cf)
            #pragma unroll
            for (int rg = 0; rg < 4; ++rg)
                *(short*)(hbf + swz_off(row0 + g * 4 + rg, (l15 + 16 * cf) * 2, 256)) =
                    f2bf(hx[cf][rg]);
    }
    __syncthreads();   // ebuf -> attn scratch transition

    // ---------------- transformer layers ----------------------------------
    for (int ly = 0; ly < NLAYER; ++ly) {
        const short* WIl = wI + (size_t)ly * 3 * HID * HID;
        const float* bI  = aib + ly * 3 * HID;
        const short* WOl = wO + (size_t)ly * HID * HID;
        const float* bO  = aob + ly * HID;
        const short* W1l = w1 + (size_t)ly * FFD * HID;
        const float* b1  = f1b + ly * FFD;
        const short* W2l = w2 + (size_t)ly * HID * FFD;
        const float* b2v = f2b + ly * HID;

        // fold attn-out bias into residual accumulator
        #pragma unroll
        for (int cf = 0; cf < 8; ++cf) {
            float bs = bO[l15 + 16 * cf];
            #pragma unroll
            for (int rg = 0; rg < 4; ++rg) hx[cf][rg] += bs;
        }

        for (int hd = 0; hd < NHEAD; ++hd) {
            // ---- QKV for this head ----
            f32x4 acc[6];
            #pragma unroll
            for (int cf = 0; cf < 6; ++cf) {
                float bs = bI[(cf >> 1) * HID + hd * HDIM + l15 + 16 * (cf & 1)];
                acc[cf] = (f32x4){bs, bs, bs, bs};
            }
            gemm1<6, 4>(acc, hbf, row0, 256, l15, g,
                [&](int cf, int kc) {
                    int colw = (cf >> 1) * HID + hd * HDIM + l15 + 16 * (cf & 1);
                    return *(const bf16x8*)(WIl + (size_t)colw * HID + kc * 32 + g * 8);
                });
            #pragma unroll
            for (int cf = 0; cf < 2; ++cf) {
                int dcol = (l15 + 16 * cf) * 2;
                #pragma unroll
                for (int rg = 0; rg < 4; ++rg) {
                    int row = row0 + g * 4 + rg;
                    *(short*)(qOh + swz_off(row, dcol, 64)) = f2bf(acc[cf][rg]);
                    *(short*)(k_l + swz_off(row, dcol, 64)) = f2bf(acc[2 + cf][rg]);
                }
                short4v pv;
                pv[0] = f2bf(acc[4 + cf][0]); pv[1] = f2bf(acc[4 + cf][1]);
                pv[2] = f2bf(acc[4 + cf][2]); pv[3] = f2bf(acc[4 + cf][3]);
                *(short4v*)(vT + swz_off(l15 + 16 * cf, (row0 + g * 4) * 2, 256)) = pv;
            }
            __syncthreads();   // k_l, vT visible to all waves

            // ---- S = Q K^T ----
            f32x4 sc[8];
            #pragma unroll
            for (int cf = 0; cf < 8; ++cf) sc[cf] = (f32x4){0.f, 0.f, 0.f, 0.f};
            gemm1<8, 1>(sc, qOh, row0, 64, l15, g,
                [&](int cf, int kc) {
                    (void)kc;
                    return *(const bf16x8*)(k_l + swz_off(l15 + 16 * cf, g * 16, 64));
                });

            // ---- softmax (registers + 4 shfl) ----
            const float SC_ = 0.17677669529663687f;
            float inv_s[4];
            #pragma unroll
            for (int rg = 0; rg < 4; ++rg) {
                float mx = -1e30f;
                #pragma unroll
                for (int cf = 0; cf < 8; ++cf) {
                    sc[cf][rg] *= SC_;
                    mx = fmaxf(mx, sc[cf][rg]);
                }
                mx = fmaxf(mx, __shfl_xor(mx, 1)); mx = fmaxf(mx, __shfl_xor(mx, 2));
                mx = fmaxf(mx, __shfl_xor(mx, 4)); mx = fmaxf(mx, __shfl_xor(mx, 8));
                float sum = 0.f;
                #pragma unroll
                for (int cf = 0; cf < 8; ++cf) {
                    float e = __expf(sc[cf][rg] - mx);
                    sc[cf][rg] = e; sum += e;
                }
                sum += __shfl_xor(sum, 1); sum += __shfl_xor(sum, 2);
                sum += __shfl_xor(sum, 4); sum += __shfl_xor(sum, 8);
                inv_s[rg] = 1.f / sum;
            }

            // ---- O = P V, k-chunked through wave-local Pch ----
            f32x4 ov[2];
            ov[0] = (f32x4){0.f, 0.f, 0.f, 0.f};
            ov[1] = (f32x4){0.f, 0.f, 0.f, 0.f};
            #pragma unroll
            for (int cc = 0; cc < 4; ++cc) {
                #pragma unroll
                for (int q = 0; q < 2; ++q) {
                    int cfi = 2 * cc + q;
                    #pragma unroll
                    for (int rg = 0; rg < 4; ++rg)
                        *(short*)(Pch + swz_off(row0 + g * 4 + rg, (l15 + 16 * q) * 2, 64)) =
                            f2bf(sc[cfi][rg] * inv_s[rg]);
                }
                gemm1<2, 1>(ov, Pch, row0, 64, l15, g,
                    [&](int cf, int kc) {
                        (void)kc;
                        return *(const bf16x8*)(vT + swz_off(l15 + 16 * cf, cc * 64 + g * 16, 256));
                    });
            }
            // ---- stage O_head (overwrites dead q), accumulate out-proj ----
            #pragma unroll
            for (int cf = 0; cf < 2; ++cf)
                #pragma unroll
                for (int rg = 0; rg < 4; ++rg)
                    *(short*)(qOh + swz_off(row0 + g * 4 + rg, (l15 + 16 * cf) * 2, 64)) =
                        f2bf(ov[cf][rg]);
            gemm1<8, 1>(hx, qOh, row0, 64, l15, g,
                [&](int cf, int kc) {
                    (void)kc;
                    int col = l15 + 16 * cf;
                    return *(const bf16x8*)(WOl + (size_t)col * HID + hd * HDIM + g * 8);
                });
            __syncthreads();   // protect k_l/vT for next head
        } // heads

        // ---- LN1, write hbf ----
        layer_norm1(hx, l1g + ly * HID, l1b + ly * HID, l15);
        #pragma unroll
        for (int cf = 0; cf < 8; ++cf)
            #pragma unroll
            for (int rg = 0; rg < 4; ++rg)
                *(short*)(hbf + swz_off(row0 + g * 4 + rg, (l15 + 16 * cf) * 2, 256)) =
                    f2bf(hx[cf][rg]);

        // ---- FF1 (relu) -> ffb (wave-local) ----
        f32x4 ff[8];
        #pragma unroll
        for (int cf = 0; cf < 8; ++cf) {
            float bs = b1[l15 + 16 * cf];
            ff[cf] = (f32x4){bs, bs, bs, bs};
        }
        gemm1<8, 4>(ff, hbf, row0, 256, l15, g,
            [&](int cf, int kc) {
                int col = l15 + 16 * cf;
                return *(const bf16x8*)(W1l + (size_t)col * HID + kc * 32 + g * 8);
            });
        #pragma unroll
        for (int cf = 0; cf < 8; ++cf)
            #pragma unroll
            for (int rg = 0; rg < 4; ++rg)
                *(short*)(ffb + swz_off(row0 + g * 4 + rg, (l15 + 16 * cf) * 2, 256)) =
                    f2bf(fmaxf(ff[cf][rg], 0.f));

        // ---- FF2 + residual + LN2 ----
        f32x4 yy[8];
        #pragma unroll
        for (int cf = 0; cf < 8; ++cf) {
            float bs = b2v[l15 + 16 * cf];
            yy[cf] = (f32x4){bs, bs, bs, bs};
        }
        gemm1<8, 4>(yy, ffb, row0, 256, l15, g,
            [&](int cf, int kc) {
                int col = l15 + 16 * cf;
                return *(const bf16x8*)(W2l + (size_t)col * FFD + kc * 32 + g * 8);
            });
        #pragma unroll
        for (int cf = 0; cf < 8; ++cf) yy[cf] += hx[cf];
        layer_norm1(yy, l2g + ly * HID, l2b + ly * HID, l15);
        #pragma unroll
        for (int cf = 0; cf < 8; ++cf) {
            hx[cf] = yy[cf];
            #pragma unroll
            for (int rg = 0; rg < 4; ++rg)
                *(short*)(hbf + swz_off(row0 + g * 4 + rg, (l15 + 16 * cf) * 2, 256)) =
                    f2bf(yy[cf][rg]);
        }
        __syncthreads();   // end of layer: ffb reads done before next k/vT writes
    } // layers

    // ---------------- pool over the 128 tokens -----------------------------
    #pragma unroll
    for (int cf = 0; cf < 8; ++cf) {
        float s = hx[cf][0] + hx[cf][1] + hx[cf][2] + hx[cf][3];
        s += __shfl_xor(s, 16); s += __shfl_xor(s, 32);
        if (g == 0) pool_s[w * 128 + l15 + 16 * cf] = s;
    }
    __syncthreads();
    if (tid < 128) {
        float s = 0.f;
        #pragma unroll
        for (int ww = 0; ww < 8; ++ww) s += pool_s[ww * 128 + tid];
        pooled[b * HID + tid] = s * (1.f / 128.f);
    }
}

// ============================================================
// final mean over neighbors + prediction head (512 threads)
// ============================================================
__global__ void final_pred(const float* __restrict__ pooled,
                           const float* __restrict__ w1, const float* __restrict__ b1,
                           const float* __restrict__ w2, const float* __restrict__ b2,
                           float* __restrict__ out)
{
    __shared__ float part[4][HID];
    __shared__ float fin[HID];
    __shared__ float hm[HID];
    const int tid = threadIdx.x;           // 512
    const int f = tid & 127, q = tid >> 7;
    float s = 0.f;
    for (int bb = q * 256; bb < (q + 1) * 256; ++bb) s += pooled[bb * HID + f];
    part[q][f] = s;
    __syncthreads();
    if (tid < HID) {
        fin[tid] = (part[0][tid] + part[1][tid] + part[2][tid] + part[3][tid])
                   * (1.f / (float)D_N);
    }
    __syncthreads();
    if (tid < HID) {
        float a = b1[tid];
        for (int k = 0; k < HID; ++k) a += fin[k] * w1[tid * HID + k];
        hm[tid] = fmaxf(a, 0.f) * w2[tid];
    }
    __syncthreads();
    if (tid == 0) {
        float z = 0.f;
        for (int j = 0; j < HID; ++j) z += hm[j];
        z += b2[0];
        out[0] = 1.f / (1.f + __expf(-z));
    }
}

// ============================================================
// launch
// ============================================================
extern "C" void kernel_launch(void* const* d_in, const int* in_sizes, int n_in,
                              void* d_out, int out_size, void* d_ws, size_t ws_size,
                              hipStream_t stream)
{
    (void)in_sizes; (void)n_in; (void)out_size; (void)ws_size;

    const int*   tgt   = (const int*)  d_in[0];
    const int*   eidx  = (const int*)  d_in[2];
    const float* eattr = (const float*)d_in[3];
    const float* ftm   = (const float*)d_in[4];
    const float* projw = (const float*)d_in[5];
    const float* projb = (const float*)d_in[6];
    const float* aiw   = (const float*)d_in[7];
    const float* aib   = (const float*)d_in[8];
    const float* aow   = (const float*)d_in[9];
    const float* aob   = (const float*)d_in[10];
    const float* l1g   = (const float*)d_in[11];
    const float* l1b   = (const float*)d_in[12];
    const float* f1w   = (const float*)d_in[13];
    const float* f1b   = (const float*)d_in[14];
    const float* f2w   = (const float*)d_in[15];
    const float* f2b   = (const float*)d_in[16];
    const float* l2g   = (const float*)d_in[17];
    const float* l2b   = (const float*)d_in[18];
    const float* pw1   = (const float*)d_in[19];
    const float* pb1   = (const float*)d_in[20];
    const float* pw2   = (const float*)d_in[21];
    const float* pb2   = (const float*)d_in[22];

    char* ws = (char*)d_ws;
    int*   order  = (int*)  (ws + OFF_ORDER);
    int*   key    = (int*)  (ws + OFF_KEY);
    int*   slot   = (int*)  (ws + OFF_SLOT);
    int*   hist   = (int*)  (ws + OFF_HIST);
    int*   tot    = (int*)  (ws + OFF_TOT);
    float* pooled = (float*)(ws + OFF_POOL);
    short* wbf    = (short*)(ws + OFF_WBF);

    init_ws      <<<dim3(1024), dim3(256),  0, stream>>>(slot, hist);
    find_neigh   <<<dim3(1),    dim3(1024), 0, stream>>>(eidx, tgt, slot);
    compute_key  <<<dim3(512),  dim3(256),  0, stream>>>(eidx, tgt, slot, key);
    hist_build   <<<dim3(2),    dim3(256),  0, stream>>>(key, hist);
    scan_pass1   <<<dim3(9),    dim3(256),  0, stream>>>(hist, tot);
    scan_pass2   <<<dim3(1),    dim3(1024), 0, stream>>>(tot);
    scan_pass3   <<<dim3(9),    dim3(256),  0, stream>>>(hist, tot);
    scatter_order<<<dim3(2),    dim3(256),  0, stream>>>(key, hist, order);
    cvt_all      <<<dim3(120),  dim3(256),  0, stream>>>(projw, aiw, aow, f1w, f2w, wbf);

    fused_mfma<<<dim3(D_N), dim3(512), 0, stream>>>(
        eattr, ftm,
        wbf + WP_OFF, projb,
        wbf + WI_OFF, aib,
        wbf + WO_OFF, aob,
        l1g, l1b,
        wbf + W1_OFF, f1b,
        wbf + W2_OFF, f2b,
        l2g, l2b,
        order, pooled);

    final_pred<<<dim3(1), dim3(512), 0, stream>>>(pooled, pw1, pb1, pw2, pb2, (float*)d_out);
}

// Round 4
// 521.184 us; speedup vs baseline: 16.6157x; 1.6176x over previous
//
#include <hip/hip_runtime.h>
#include <cstdint>
#include <cstddef>

// ---------------- problem constants ----------------
#define D_N     1024
#define K_S     128
#define EDIM    384
#define HID     128
#define NHEAD   4
#define HDIM    32
#define FFD     128
#define NLAYER  2
#define ETOT    (D_N * K_S)
#define NNODES  200000
#define NBINS   (2 * D_N + 2)
#define NCH     512
#define CHL     (ETOT / NCH)

// ---------------- workspace layout (bytes) ----------------
#define OFF_ORDER 0u
#define OFF_KEY   (1u << 19)
#define OFF_SLOT  (1u << 20)
#define OFF_HIST  (1u << 21)               // 2050*512*4 = 4,198,400
#define OFF_TOT   (OFF_HIST + NBINS * NCH * 4)
#define OFF_POOL  (7u << 20)
// bf16 weights overwrite hist AFTER the sort (stream-ordered):
#define OFF_WBF   OFF_HIST
#define WP_OFF 0
#define WI_OFF 49152
#define WO_OFF 147456
#define W1_OFF 180224
#define W2_OFF 212992
#define WTOT   245760

typedef __attribute__((ext_vector_type(8))) short  bf16x8;
typedef __attribute__((ext_vector_type(4))) short  short4v;
typedef __attribute__((ext_vector_type(4))) float  f32x4;

__device__ __forceinline__ short f2bf(float f) {
    union { float f; unsigned u; } v; v.f = f;
    unsigned r = v.u + 0x7fffu + ((v.u >> 16) & 1u);
    return (short)(r >> 16);
}
__device__ __forceinline__ int swz_off(int r, int byteInRow, int strideBytes) {
    return (r * strideBytes + byteInRow) ^ ((r & 7) << 4);
}

// ============================================================
// preprocessing
// ============================================================
__global__ void init_ws(int* __restrict__ slot, int* __restrict__ hist)
{
    int idx = blockIdx.x * blockDim.x + threadIdx.x;
    int stride = gridDim.x * blockDim.x;
    for (int i = idx; i < NBINS * NCH; i += stride) hist[i] = 0;
    for (int i = idx; i < NNODES; i += stride) slot[i] = D_N;
}

__global__ void find_neigh(const int* __restrict__ eidx,
                           const int* __restrict__ tgt_idx,
                           int* __restrict__ slot)
{
    __shared__ int wtot[16];
    __shared__ int wbase_s[16];
    __shared__ int neigh[D_N];
    const int tid  = threadIdx.x;          // 1024
    const int lane = tid & 63;
    const int wv   = tid >> 6;
    const int tgt  = tgt_idx[0];
    const int* src = eidx;
    const int* dst = eidx + ETOT;
    const int epc  = ETOT / 1024;          // 128
    const int e0   = tid * epc;

    int c = 0;
    const int4* s4 = (const int4*)(src + e0);
    #pragma unroll 8
    for (int i = 0; i < epc / 4; ++i) {
        int4 v = s4[i];
        c += (v.x == tgt) + (v.y == tgt) + (v.z == tgt) + (v.w == tgt);
    }
    // wave inclusive scan
    int incl = c;
    #pragma unroll
    for (int d = 1; d < 64; d <<= 1) {
        int t = __shfl_up(incl, d, 64);
        if (lane >= d) incl += t;
    }
    if (lane == 63) wtot[wv] = incl;
    __syncthreads();
    if (tid < 16) {
        int s = 0;
        for (int j = 0; j < tid; ++j) s += wtot[j];
        wbase_s[tid] = s;
    }
    __syncthreads();
    int r = wbase_s[wv] + incl - c;        // exclusive prefix
    for (int e = e0; e < e0 + epc; ++e) {
        if (src[e] == tgt) { if (r < D_N) neigh[r] = dst[e]; ++r; }
    }
    __syncthreads();
    int total = wbase_s[15] + wtot[15];
    if (tid < total && tid < D_N) slot[neigh[tid]] = tid;
}

__global__ void compute_key(const int* __restrict__ eidx,
                            const int* __restrict__ tgt_idx,
                            const int* __restrict__ slot,
                            int* __restrict__ key)
{
    int e = blockIdx.x * 256 + threadIdx.x;
    if (e >= ETOT) return;
    int tgt = tgt_idx[0];
    key[e] = slot[eidx[ETOT + e]] * 2 + ((eidx[e] != tgt) ? 1 : 0);
}

__global__ void hist_build(const int* __restrict__ key, int* __restrict__ hist)
{
    const int c = blockIdx.x * 256 + threadIdx.x;
    if (c >= NCH) return;
    const int4* kp = (const int4*)(key + c * CHL);
    int cur = -1, run = 0;
    for (int i = 0; i < CHL / 4; ++i) {
        int4 k4 = kp[i];
        #pragma unroll
        for (int j = 0; j < 4; ++j) {
            int k = (j == 0) ? k4.x : (j == 1) ? k4.y : (j == 2) ? k4.z : k4.w;
            if (k == cur) { ++run; }
            else {
                if (run) hist[cur * NCH + c] += run;
                cur = k; run = 1;
            }
        }
    }
    if (run) hist[cur * NCH + c] += run;
}

__global__ void scan_pass1(const int* __restrict__ hist, int* __restrict__ tot)
{
    int b = blockIdx.x * 256 + threadIdx.x;
    if (b >= NBINS) return;
    const int4* h = (const int4*)(hist + b * NCH);
    int s = 0;
    #pragma unroll 4
    for (int c = 0; c < NCH / 4; ++c) { int4 v = h[c]; s += v.x + v.y + v.z + v.w; }
    tot[b] = s;
}

#define SCN 2176
__global__ void scan_pass2(int* __restrict__ tot)
{
    __shared__ int A[SCN];
    __shared__ int B[SCN];
    const int tid = threadIdx.x;   // 1024
    for (int i = tid; i < SCN; i += 1024) A[i] = (i < NBINS) ? tot[i] : 0;
    __syncthreads();
    int* cur = A; int* nxt = B;
    for (int s = 1; s < SCN; s <<= 1) {
        for (int i = tid; i < SCN; i += 1024) nxt[i] = (i >= s) ? cur[i] + cur[i - s] : cur[i];
        __syncthreads();
        int* t = cur; cur = nxt; nxt = t;
    }
    for (int i = tid; i < NBINS; i += 1024) tot[i] = (i == 0) ? 0 : cur[i - 1];
}

// one wave per bin: lane l owns 8 consecutive chunk-counters
__global__ void scan_pass3(int* __restrict__ hist, const int* __restrict__ base)
{
    const int wvg  = (blockIdx.x * blockDim.x + threadIdx.x) >> 6;
    const int lane = threadIdx.x & 63;
    if (wvg >= NBINS) return;
    int* h = hist + wvg * NCH + lane * 8;
    int4 a = *(int4*)h;
    int4 b4 = *(int4*)(h + 4);
    int ls = a.x + a.y + a.z + a.w + b4.x + b4.y + b4.z + b4.w;
    int incl = ls;
    #pragma unroll
    for (int d = 1; d < 64; d <<= 1) {
        int t = __shfl_up(incl, d, 64);
        if (lane >= d) incl += t;
    }
    int run = base[wvg] + incl - ls;
    int4 o1, o2;
    o1.x = run; run += a.x;  o1.y = run; run += a.y;
    o1.z = run; run += a.z;  o1.w = run; run += a.w;
    o2.x = run; run += b4.x; o2.y = run; run += b4.y;
    o2.z = run; run += b4.z; o2.w = run; run += b4.w;
    *(int4*)h = o1;
    *(int4*)(h + 4) = o2;
}

__global__ void scatter_order(const int* __restrict__ key,
                              int* __restrict__ hist,
                              int* __restrict__ order)
{
    const int c = blockIdx.x * 256 + threadIdx.x;
    if (c >= NCH) return;
    const int e0 = c * CHL;
    const int4* kp = (const int4*)(key + e0);
    int cur = -1, pos = 0;
    for (int i = 0; i < CHL / 4; ++i) {
        int4 k4 = kp[i];
        #pragma unroll
        for (int j = 0; j < 4; ++j) {
            int k = (j == 0) ? k4.x : (j == 1) ? k4.y : (j == 2) ? k4.z : k4.w;
            if (k != cur) {
                if (cur >= 0) hist[cur * NCH + c] = pos;
                cur = k;
                pos = hist[k * NCH + c];
            }
            if (pos >= 0 && pos < ETOT) order[pos] = e0 + i * 4 + j;
            ++pos;
        }
    }
    if (cur >= 0) hist[cur * NCH + c] = pos;
}

__global__ void cvt_all(const float* __restrict__ p0, const float* __restrict__ p1,
                        const float* __restrict__ p2, const float* __restrict__ p3,
                        const float* __restrict__ p4, short* __restrict__ wbf)
{
    int i = (blockIdx.x * 256 + threadIdx.x) * 8;
    if (i >= WTOT) return;
    const float* s;
    if      (i < WI_OFF) s = p0 + i;
    else if (i < WO_OFF) s = p1 + (i - WI_OFF);
    else if (i < W1_OFF) s = p2 + (i - WO_OFF);
    else if (i < W2_OFF) s = p3 + (i - W1_OFF);
    else                 s = p4 + (i - W2_OFF);
    float4 a = *(const float4*)s;
    float4 b = *(const float4*)(s + 4);
    bf16x8 o;
    o[0] = f2bf(a.x); o[1] = f2bf(a.y); o[2] = f2bf(a.z); o[3] = f2bf(a.w);
    o[4] = f2bf(b.x); o[5] = f2bf(b.y); o[6] = f2bf(b.z); o[7] = f2bf(b.w);
    *(bf16x8*)(wbf + i) = o;
}

// ============================================================
// MFMA helpers
// ============================================================
template<int CF, int KC, typename GetB>
__device__ __forceinline__ void gemm1(f32x4 (&acc)[CF],
    const char* aB, int aRow0, int aStride, int l15, int g, GetB getB)
{
    #pragma unroll
    for (int kc = 0; kc < KC; ++kc) {
        bf16x8 a = *(const bf16x8*)(aB + swz_off(aRow0 + l15, kc * 64 + g * 16, aStride));
        #pragma unroll
        for (int cf = 0; cf < CF; ++cf)
            acc[cf] = __builtin_amdgcn_mfma_f32_16x16x32_bf16(a, getB(cf, kc), acc[cf], 0, 0, 0);
    }
}

// stage a bf16 weight matrix (row-major, ROWB bytes/row) into swizzled LDS
template<int ROWB>
__device__ __forceinline__ void stage_w(const char* __restrict__ gsrc, char* ldst,
                                        int nbytes, int tid)
{
    #pragma unroll 4
    for (int u = tid * 16; u < nbytes; u += 512 * 16) {
        int row = u / ROWB;
        int in  = u - row * ROWB;
        *(bf16x8*)(ldst + swz_off(row, in, ROWB)) = *(const bf16x8*)(gsrc + u);
    }
}

__device__ __forceinline__ void layer_norm1(f32x4 (&x)[8],
    const float* __restrict__ gg, const float* __restrict__ bb, int l15)
{
    float gv[8], bv[8];
    #pragma unroll
    for (int cf = 0; cf < 8; ++cf) { gv[cf] = gg[l15 + 16 * cf]; bv[cf] = bb[l15 + 16 * cf]; }
    #pragma unroll
    for (int rg = 0; rg < 4; ++rg) {
        float s = 0.f;
        #pragma unroll
        for (int cf = 0; cf < 8; ++cf) s += x[cf][rg];
        s += __shfl_xor(s, 1); s += __shfl_xor(s, 2);
        s += __shfl_xor(s, 4); s += __shfl_xor(s, 8);
        float mean = s * (1.f / 128.f);
        float v = 0.f;
        #pragma unroll
        for (int cf = 0; cf < 8; ++cf) { float d = x[cf][rg] - mean; v += d * d; }
        v += __shfl_xor(v, 1); v += __shfl_xor(v, 2);
        v += __shfl_xor(v, 4); v += __shfl_xor(v, 8);
        float rs = rsqrtf(v * (1.f / 128.f) + 1e-5f);
        #pragma unroll
        for (int cf = 0; cf < 8; ++cf)
            x[cf][rg] = (x[cf][rg] - mean) * rs * gv[cf] + bv[cf];
    }
}

// ============================================================
// fused transformer: 1 block = 1 neighbor; 512 thr = 8 waves x 16 rows.
// 160 KB LDS: weights staged per-phase -> B operands from LDS, not L2.
// ============================================================
#define LDS_TOTAL 163840
__global__ __launch_bounds__(512, 2) void fused_mfma(
    const float* __restrict__ edge_attrs,
    const float* __restrict__ ftm,
    const short* __restrict__ wP, const float* __restrict__ projb,
    const short* __restrict__ wI, const float* __restrict__ aib,
    const short* __restrict__ wO, const float* __restrict__ aob,
    const float* __restrict__ l1g, const float* __restrict__ l1b,
    const short* __restrict__ w1, const float* __restrict__ f1b,
    const short* __restrict__ w2, const float* __restrict__ f2b,
    const float* __restrict__ l2g, const float* __restrict__ l2b,
    const int*   __restrict__ order,
    float*       __restrict__ pooled)
{
    __shared__ __align__(16) char sm[LDS_TOTAL];
    char* hbf  = sm;                        // 32 KB  [128 tok][256 B] swz
    char* wbuf = sm + 32768;                // 96 KB  weight staging
    char* act  = sm + 131072;               // 32 KB  activation scratch
    char* k_l  = act;                       //  8 KB  [128][64 B]   (x-wave)
    char* vT   = act + 8192;                //  8 KB  [32][256 B]   (x-wave)
    char* qOh  = act + 16384;               //  8 KB  q then O_head (wave-local)
    char* Pch  = act + 24576;               //  8 KB  P chunk       (wave-local)
    char* ebuf = act;                       // 32 KB  proj staging  (wave-local)
    char* ffb  = act;                       // 32 KB  ff1 staging   (wave-local)
    float* pool_s = (float*)act;            // [8][128] f32 (after barrier)

    const int tid  = threadIdx.x;
    const int w    = tid >> 6;              // 0..7
    const int l    = tid & 63;
    const int l15  = l & 15;
    const int g    = l >> 4;
    const int row0 = 16 * w;
    const int b    = blockIdx.x;

    f32x4 hx[8];

    // ---------------- proj: h = rows @ projW^T + b (+ marker) -------------
    {
        #pragma unroll
        for (int cf = 0; cf < 8; ++cf) {
            float bs = projb[l15 + 16 * cf];
            hx[cf] = (f32x4){bs, bs, bs, bs};
        }
        const int r_off = l >> 2;           // 0..15
        const int coff  = (l & 3) * 32;
        const int row   = row0 + r_off;
        const int rowIdx = order[b * K_S + row];
        const float* arow = edge_attrs + (size_t)rowIdx * EDIM;

        float4 v[8];
        #pragma unroll
        for (int j = 0; j < 8; ++j) v[j] = *(const float4*)(arow + coff + j * 4);

        stage_w<768>((const char*)wP, wbuf, 98304, tid);   // proj weights
        __syncthreads();

        #pragma unroll
        for (int ch = 0; ch < 3; ++ch) {
            #pragma unroll
            for (int j = 0; j < 4; ++j) {
                float4 a = v[2 * j], c = v[2 * j + 1];
                bf16x8 pk;
                pk[0] = f2bf(a.x); pk[1] = f2bf(a.y); pk[2] = f2bf(a.z); pk[3] = f2bf(a.w);
                pk[4] = f2bf(c.x); pk[5] = f2bf(c.y); pk[6] = f2bf(c.z); pk[7] = f2bf(c.w);
                *(bf16x8*)(ebuf + swz_off(row, coff * 2 + j * 16, 256)) = pk;
            }
            if (ch < 2) {
                #pragma unroll
                for (int j = 0; j < 8; ++j)
                    v[j] = *(const float4*)(arow + (ch + 1) * 128 + coff + j * 4);
            }
            gemm1<8, 4>(hx, ebuf, row0, 256, l15, g,
                [&](int cf, int kc) {
                    return *(const bf16x8*)(wbuf +
                        swz_off(l15 + 16 * cf, ch * 256 + kc * 64 + g * 16, 768));
                });
        }
        if (w == 0 && g == 0) {
            #pragma unroll
            for (int cf = 0; cf < 8; ++cf) hx[cf][0] += ftm[l15 + 16 * cf];
        }
        #pragma unroll
        for (int cf = 0; cf < 8; ++cf)
            #pragma unroll
            for (int rg = 0; rg < 4; ++rg)
                *(short*)(hbf + swz_off(row0 + g * 4 + rg, (l15 + 16 * cf) * 2, 256)) =
                    f2bf(hx[cf][rg]);
    }
    __syncthreads();   // proj done: wbuf + act free for layer phase

    // ---------------- transformer layers ----------------------------------
    for (int ly = 0; ly < NLAYER; ++ly) {
        const short* WIl = wI + (size_t)ly * 3 * HID * HID;
        const float* bI  = aib + ly * 3 * HID;
        const short* WOl = wO + (size_t)ly * HID * HID;
        const float* bO  = aob + ly * HID;
        const short* W1l = w1 + (size_t)ly * FFD * HID;
        const float* b1  = f1b + ly * FFD;
        const short* W2l = w2 + (size_t)ly * HID * FFD;
        const float* b2v = f2b + ly * HID;

        stage_w<256>((const char*)WIl, wbuf, 98304, tid);   // QKV weights

        // fold attn-out bias into residual accumulator
        #pragma unroll
        for (int cf = 0; cf < 8; ++cf) {
            float bs = bO[l15 + 16 * cf];
            #pragma unroll
            for (int rg = 0; rg < 4; ++rg) hx[cf][rg] += bs;
        }
        __syncthreads();   // QKV weights visible

        for (int hd = 0; hd < NHEAD; ++hd) {
            // ---- QKV for this head (B from LDS) ----
            f32x4 acc[6];
            #pragma unroll
            for (int cf = 0; cf < 6; ++cf) {
                float bs = bI[(cf >> 1) * HID + hd * HDIM + l15 + 16 * (cf & 1)];
                acc[cf] = (f32x4){bs, bs, bs, bs};
            }
            gemm1<6, 4>(acc, hbf, row0, 256, l15, g,
                [&](int cf, int kc) {
                    int colw = (cf >> 1) * HID + hd * HDIM + l15 + 16 * (cf & 1);
                    return *(const bf16x8*)(wbuf + swz_off(colw, kc * 64 + g * 16, 256));
                });
            #pragma unroll
            for (int cf = 0; cf < 2; ++cf) {
                int dcol = (l15 + 16 * cf) * 2;
                #pragma unroll
                for (int rg = 0; rg < 4; ++rg) {
                    int row = row0 + g * 4 + rg;
                    *(short*)(qOh + swz_off(row, dcol, 64)) = f2bf(acc[cf][rg]);
                    *(short*)(k_l + swz_off(row, dcol, 64)) = f2bf(acc[2 + cf][rg]);
                }
                short4v pv;
                pv[0] = f2bf(acc[4 + cf][0]); pv[1] = f2bf(acc[4 + cf][1]);
                pv[2] = f2bf(acc[4 + cf][2]); pv[3] = f2bf(acc[4 + cf][3]);
                *(short4v*)(vT + swz_off(l15 + 16 * cf, (row0 + g * 4) * 2, 256)) = pv;
            }
            __syncthreads();   // k_l, vT visible to all waves

            // ---- S = Q K^T ----
            f32x4 sc[8];
            #pragma unroll
            for (int cf = 0; cf < 8; ++cf) sc[cf] = (f32x4){0.f, 0.f, 0.f, 0.f};
            gemm1<8, 1>(sc, qOh, row0, 64, l15, g,
                [&](int cf, int kc) {
                    (void)kc;
                    return *(const bf16x8*)(k_l + swz_off(l15 + 16 * cf, g * 16, 64));
                });

            // ---- softmax ----
            const float SC_ = 0.17677669529663687f;
            float inv_s[4];
            #pragma unroll
            for (int rg = 0; rg < 4; ++rg) {
                float mx = -1e30f;
                #pragma unroll
                for (int cf = 0; cf < 8; ++cf) {
                    sc[cf][rg] *= SC_;
                    mx = fmaxf(mx, sc[cf][rg]);
                }
                mx = fmaxf(mx, __shfl_xor(mx, 1)); mx = fmaxf(mx, __shfl_xor(mx, 2));
                mx = fmaxf(mx, __shfl_xor(mx, 4)); mx = fmaxf(mx, __shfl_xor(mx, 8));
                float sum = 0.f;
                #pragma unroll
                for (int cf = 0; cf < 8; ++cf) {
                    float e = __expf(sc[cf][rg] - mx);
                    sc[cf][rg] = e; sum += e;
                }
                sum += __shfl_xor(sum, 1); sum += __shfl_xor(sum, 2);
                sum += __shfl_xor(sum, 4); sum += __shfl_xor(sum, 8);
                inv_s[rg] = 1.f / sum;
            }

            // ---- O = P V via wave-local P chunks ----
            f32x4 ov[2];
            ov[0] = (f32x4){0.f, 0.f, 0.f, 0.f};
            ov[1] = (f32x4){0.f, 0.f, 0.f, 0.f};
            #pragma unroll
            for (int cc = 0; cc < 4; ++cc) {
                #pragma unroll
                for (int q = 0; q < 2; ++q) {
                    int cfi = 2 * cc + q;
                    #pragma unroll
                    for (int rg = 0; rg < 4; ++rg)
                        *(short*)(Pch + swz_off(row0 + g * 4 + rg, (l15 + 16 * q) * 2, 64)) =
                            f2bf(sc[cfi][rg] * inv_s[rg]);
                }
                gemm1<2, 1>(ov, Pch, row0, 64, l15, g,
                    [&](int cf, int kc) {
                        (void)kc;
                        return *(const bf16x8*)(vT + swz_off(l15 + 16 * cf, cc * 64 + g * 16, 256));
                    });
            }
            // ---- O_head -> qOh (dead q), accumulate out-proj into hx ----
            #pragma unroll
            for (int cf = 0; cf < 2; ++cf)
                #pragma unroll
                for (int rg = 0; rg < 4; ++rg)
                    *(short*)(qOh + swz_off(row0 + g * 4 + rg, (l15 + 16 * cf) * 2, 64)) =
                        f2bf(ov[cf][rg]);
            gemm1<8, 1>(hx, qOh, row0, 64, l15, g,
                [&](int cf, int kc) {
                    (void)kc;
                    int col = l15 + 16 * cf;
                    return *(const bf16x8*)(WOl + (size_t)col * HID + hd * HDIM + g * 8);
                });
            __syncthreads();   // protect k_l/vT for next head
        } // heads

        // ---- stage FF weights (loads hide under LN) ----
        stage_w<256>((const char*)W1l, wbuf,         32768, tid);
        stage_w<256>((const char*)W2l, wbuf + 32768, 32768, tid);

        // ---- LN1, write hbf ----
        layer_norm1(hx, l1g + ly * HID, l1b + ly * HID, l15);
        #pragma unroll
        for (int cf = 0; cf < 8; ++cf)
            #pragma unroll
            for (int rg = 0; rg < 4; ++rg)
                *(short*)(hbf + swz_off(row0 + g * 4 + rg, (l15 + 16 * cf) * 2, 256)) =
                    f2bf(hx[cf][rg]);
        __syncthreads();   // FF weights visible

        // ---- FF1 (relu) -> ffb (wave-local) ----
        f32x4 ff[8];
        #pragma unroll
        for (int cf = 0; cf < 8; ++cf) {
            float bs = b1[l15 + 16 * cf];
            ff[cf] = (f32x4){bs, bs, bs, bs};
        }
        gemm1<8, 4>(ff, hbf, row0, 256, l15, g,
            [&](int cf, int kc) {
                return *(const bf16x8*)(wbuf + swz_off(l15 + 16 * cf, kc * 64 + g * 16, 256));
            });
        #pragma unroll
        for (int cf = 0; cf < 8; ++cf)
            #pragma unroll
            for (int rg = 0; rg < 4; ++rg)
                *(short*)(ffb + swz_off(row0 + g * 4 + rg, (l15 + 16 * cf) * 2, 256)) =
                    f2bf(fmaxf(ff[cf][rg], 0.f));

        // ---- FF2 + residual + LN2 ----
        f32x4 yy[8];
        #pragma unroll
        for (int cf = 0; cf < 8; ++cf) {
            float bs = b2v[l15 + 16 * cf];
            yy[cf] = (f32x4){bs, bs, bs, bs};
        }
        gemm1<8, 4>(yy, ffb, row0, 256, l15, g,
            [&](int cf, int kc) {
                return *(const bf16x8*)(wbuf + 32768 +
                    swz_off(l15 + 16 * cf, kc * 64 + g * 16, 256));
            });
        #pragma unroll
        for (int cf = 0; cf < 8; ++cf) yy[cf] += hx[cf];
        layer_norm1(yy, l2g + ly * HID, l2b + ly * HID, l15);
        #pragma unroll
        for (int cf = 0; cf < 8; ++cf) {
            hx[cf] = yy[cf];
            #pragma unroll
            for (int rg = 0; rg < 4; ++rg)
                *(short*)(hbf + swz_off(row0 + g * 4 + rg, (l15 + 16 * cf) * 2, 256)) =
                    f2bf(yy[cf][rg]);
        }
        __syncthreads();   // end of layer: wbuf/act free
    } // layers

    // ---------------- pool over the 128 tokens -----------------------------
    #pragma unroll
    for (int cf = 0; cf < 8; ++cf) {
        float s = hx[cf][0] + hx[cf][1] + hx[cf][2] + hx[cf][3];
        s += __shfl_xor(s, 16); s += __shfl_xor(s, 32);
        if (g == 0) pool_s[w * 128 + l15 + 16 * cf] = s;
    }
    __syncthreads();
    if (tid < 128) {
        float s = 0.f;
        #pragma unroll
        for (int ww = 0; ww < 8; ++ww) s += pool_s[ww * 128 + tid];
        pooled[b * HID + tid] = s * (1.f / 128.f);
    }
}

// ============================================================
// final mean over neighbors + prediction head
// ============================================================
__global__ void final_pred(const float* __restrict__ pooled,
                           const float* __restrict__ w1, const float* __restrict__ b1,
                           const float* __restrict__ w2, const float* __restrict__ b2,
                           float* __restrict__ out)
{
    __shared__ float part[4][HID];
    __shared__ float fin[HID];
    __shared__ float hm[HID];
    const int tid = threadIdx.x;           // 512
    const int f = tid & 127, q = tid >> 7;
    float s = 0.f;
    for (int bb = q * 256; bb < (q + 1) * 256; ++bb) s += pooled[bb * HID + f];
    part[q][f] = s;
    __syncthreads();
    if (tid < HID) {
        fin[tid] = (part[0][tid] + part[1][tid] + part[2][tid] + part[3][tid])
                   * (1.f / (float)D_N);
    }
    __syncthreads();
    if (tid < HID) {
        float a = b1[tid];
        for (int k = 0; k < HID; ++k) a += fin[k] * w1[tid * HID + k];
        hm[tid] = fmaxf(a, 0.f) * w2[tid];
    }
    __syncthreads();
    if (tid == 0) {
        float z = 0.f;
        for (int j = 0; j < HID; ++j) z += hm[j];
        z += b2[0];
        out[0] = 1.f / (1.f + __expf(-z));
    }
}

// ============================================================
// launch
// ============================================================
extern "C" void kernel_launch(void* const* d_in, const int* in_sizes, int n_in,
                              void* d_out, int out_size, void* d_ws, size_t ws_size,
                              hipStream_t stream)
{
    (void)in_sizes; (void)n_in; (void)out_size; (void)ws_size;

    const int*   tgt   = (const int*)  d_in[0];
    const int*   eidx  = (const int*)  d_in[2];
    const float* eattr = (const float*)d_in[3];
    const float* ftm   = (const float*)d_in[4];
    const float* projw = (const float*)d_in[5];
    const float* projb = (const float*)d_in[6];
    const float* aiw   = (const float*)d_in[7];
    const float* aib   = (const float*)d_in[8];
    const float* aow   = (const float*)d_in[9];
    const float* aob   = (const float*)d_in[10];
    const float* l1g   = (const float*)d_in[11];
    const float* l1b   = (const float*)d_in[12];
    const float* f1w   = (const float*)d_in[13];
    const float* f1b   = (const float*)d_in[14];
    const float* f2w   = (const float*)d_in[15];
    const float* f2b   = (const float*)d_in[16];
    const float* l2g   = (const float*)d_in[17];
    const float* l2b   = (const float*)d_in[18];
    const float* pw1   = (const float*)d_in[19];
    const float* pb1   = (const float*)d_in[20];
    const float* pw2   = (const float*)d_in[21];
    const float* pb2   = (const float*)d_in[22];

    char* ws = (char*)d_ws;
    int*   order  = (int*)  (ws + OFF_ORDER);
    int*   key    = (int*)  (ws + OFF_KEY);
    int*   slot   = (int*)  (ws + OFF_SLOT);
    int*   hist   = (int*)  (ws + OFF_HIST);
    int*   tot    = (int*)  (ws + OFF_TOT);
    float* pooled = (float*)(ws + OFF_POOL);
    short* wbf    = (short*)(ws + OFF_WBF);

    init_ws      <<<dim3(1024), dim3(256),  0, stream>>>(slot, hist);
    find_neigh   <<<dim3(1),    dim3(1024), 0, stream>>>(eidx, tgt, slot);
    compute_key  <<<dim3(512),  dim3(256),  0, stream>>>(eidx, tgt, slot, key);
    hist_build   <<<dim3(2),    dim3(256),  0, stream>>>(key, hist);
    scan_pass1   <<<dim3(9),    dim3(256),  0, stream>>>(hist, tot);
    scan_pass2   <<<dim3(1),    dim3(1024), 0, stream>>>(tot);
    scan_pass3   <<<dim3(513),  dim3(256),  0, stream>>>(hist, tot);
    scatter_order<<<dim3(2),    dim3(256),  0, stream>>>(key, hist, order);
    cvt_all      <<<dim3(120),  dim3(256),  0, stream>>>(projw, aiw, aow, f1w, f2w, wbf);

    fused_mfma<<<dim3(D_N), dim3(512), 0, stream>>>(
        eattr, ftm,
        wbf + WP_OFF, projb,
        wbf + WI_OFF, aib,
        wbf + WO_OFF, aob,
        l1g, l1b,
        wbf + W1_OFF, f1b,
        wbf + W2_OFF, f2b,
        l2g, l2b,
        order, pooled);

    final_pred<<<dim3(1), dim3(512), 0, stream>>>(pooled, pw1, pb1, pw2, pb2, (float*)d_out);
}